// Round 1
// baseline (6109.261 us; speedup 1.0000x reference)
//
#include <hip/hip_runtime.h>
#include <hip/hip_bf16.h>

typedef __hip_bfloat16 bf16;

constexpr int S = 1024, CA = 768, CS = 384, CZ = 128, NHID = 1536;
constexpr int NBLK = 4, NHEAD = 16, DH = 48;
constexpr float EPS = 1e-5f;

#define DEV static __device__ __forceinline__

DEV float sigmoidf_(float x) { return 1.0f / (1.0f + __expf(-x)); }

DEV float wred_max(float v) {
#pragma unroll
  for (int o = 32; o; o >>= 1) v = fmaxf(v, __shfl_xor(v, o));
  return v;
}
DEV float wred_sum(float v) {
#pragma unroll
  for (int o = 32; o; o >>= 1) v += __shfl_xor(v, o);
  return v;
}

// ---------------- row LayerNorm (no affine unless w) ----------------
template <int C>
__global__ __launch_bounds__(256) void rowln_kernel(const float* __restrict__ x,
                                                    const float* __restrict__ w,
                                                    float* __restrict__ out) {
  constexpr int C4 = C / 4;
  __shared__ float red[8];
  const int t = threadIdx.x;
  const size_t row = blockIdx.x;
  const float4* xr = (const float4*)(x + row * C);
  float4 v = make_float4(0.f, 0.f, 0.f, 0.f);
  if (t < C4) v = xr[t];
  float sum = v.x + v.y + v.z + v.w;
  float sq = v.x * v.x + v.y * v.y + v.z * v.z + v.w * v.w;
  sum = wred_sum(sum);
  sq = wred_sum(sq);
  const int wv = t >> 6;
  if ((t & 63) == 0) { red[2 * wv] = sum; red[2 * wv + 1] = sq; }
  __syncthreads();
  sum = red[0] + red[2] + red[4] + red[6];
  sq = red[1] + red[3] + red[5] + red[7];
  const float m = sum / C;
  const float rstd = rsqrtf(sq / C - m * m + EPS);
  if (t < C4) {
    float4 o;
    o.x = (v.x - m) * rstd; o.y = (v.y - m) * rstd;
    o.z = (v.z - m) * rstd; o.w = (v.w - m) * rstd;
    if (w) {
      const float4 w4 = ((const float4*)w)[t];
      o.x *= w4.x; o.y *= w4.y; o.z *= w4.z; o.w *= w4.w;
    }
    ((float4*)(out + row * C))[t] = o;
  }
}

// ---------------- combine LN_z affine into wpb ----------------
// W2[c][col] with col = blk*16+h ; bias2[col]
__global__ __launch_bounds__(256) void prep_w2(const float* __restrict__ ln_z_w,
                                               const float* __restrict__ ln_z_b,
                                               const float* __restrict__ wpb,
                                               float* __restrict__ W2,
                                               float* __restrict__ bias2) {
  const int t = threadIdx.x;
  for (int f = t; f < CZ * 64; f += 256) {
    const int c = f >> 6, col = f & 63, blk = col >> 4, h = col & 15;
    W2[f] = ln_z_w[blk * CZ + c] * wpb[(blk * CZ + c) * NHEAD + h];
  }
  if (t < 64) {
    const int blk = t >> 4, h = t & 15;
    float sum = 0.f;
    for (int c = 0; c < CZ; ++c)
      sum += ln_z_b[blk * CZ + c] * wpb[(blk * CZ + c) * NHEAD + h];
    bias2[t] = sum;
  }
}

// ---------------- z pair-bias: LN(z) @ W2 + bias2 + beta -> bf16 [64][S][S] --------
__global__ __launch_bounds__(256) void zbias_kernel(const float* __restrict__ z,
                                                    const float* __restrict__ beta,
                                                    const float* __restrict__ W2,
                                                    const float* __restrict__ bias2,
                                                    bf16* __restrict__ bias_all) {
  __shared__ bf16 ztb[64][132];
  __shared__ float W2s[CZ][64];
  __shared__ float betas[64][17];
  __shared__ float bias2s[64];
  const int t = threadIdx.x;
  const int i = blockIdx.y, j0 = blockIdx.x * 64;
  {
    const float4* src = (const float4*)W2;
    float4* dst = (float4*)&W2s[0][0];
    for (int f = t; f < CZ * 16; f += 256) dst[f] = src[f];
  }
  if (t < 64) bias2s[t] = bias2[t];
  {
    const int j = t >> 2, h4 = t & 3;
    const float4 bv = *(const float4*)(beta + ((size_t)i * S + j0 + j) * NHEAD + 4 * h4);
    betas[j][4 * h4 + 0] = bv.x; betas[j][4 * h4 + 1] = bv.y;
    betas[j][4 * h4 + 2] = bv.z; betas[j][4 * h4 + 3] = bv.w;
  }
  // LN of 64 z rows, one quad of lanes per row
  {
    const int p = t >> 2, q = t & 3;
    const float* zr = z + ((size_t)i * S + j0 + p) * CZ + q * 32;
    float vals[32];
    float sum = 0.f, sq = 0.f;
#pragma unroll
    for (int k4 = 0; k4 < 8; ++k4) {
      const float4 xv = *(const float4*)(zr + 4 * k4);
      vals[4 * k4 + 0] = xv.x; vals[4 * k4 + 1] = xv.y;
      vals[4 * k4 + 2] = xv.z; vals[4 * k4 + 3] = xv.w;
      sum += xv.x + xv.y + xv.z + xv.w;
      sq += xv.x * xv.x + xv.y * xv.y + xv.z * xv.z + xv.w * xv.w;
    }
    sum += __shfl_xor(sum, 1); sum += __shfl_xor(sum, 2);
    sq += __shfl_xor(sq, 1); sq += __shfl_xor(sq, 2);
    const float m = sum / CZ;
    const float rstd = rsqrtf(sq / CZ - m * m + EPS);
#pragma unroll
    for (int c = 0; c < 32; ++c)
      ztb[p][q * 32 + c] = __float2bfloat16((vals[c] - m) * rstd);
  }
  __syncthreads();
  const int tx = t & 15, ty = t >> 4;
  float acc[4][4] = {};
  for (int c = 0; c < CZ; ++c) {
    float av[4];
#pragma unroll
    for (int u = 0; u < 4; ++u) av[u] = __bfloat162float(ztb[4 * ty + u][c]);
    const float4 w4 = *(const float4*)&W2s[c][4 * tx];
#pragma unroll
    for (int u = 0; u < 4; ++u) {
      acc[u][0] += av[u] * w4.x; acc[u][1] += av[u] * w4.y;
      acc[u][2] += av[u] * w4.z; acc[u][3] += av[u] * w4.w;
    }
  }
#pragma unroll
  for (int ii = 0; ii < 4; ++ii) {
    const int j = 4 * ty + ii;
#pragma unroll
    for (int jj = 0; jj < 4; ++jj) {
      const int col = 4 * tx + jj;
      const float val = acc[ii][jj] + bias2s[col] + betas[j][col & 15];
      bias_all[(size_t)col * S * S + (size_t)i * S + j0 + j] = __float2bfloat16(val);
    }
  }
}

// ---------------- generic f32 GEMM: C = act(A@B + bias) ----------------
// tile 128x128, BK=16, 256 threads, 8x8 per thread. ACT: 0 none, 1 sigmoid
template <int ACT>
__global__ __launch_bounds__(256) void gemm128(const float* __restrict__ A,
                                               const float* __restrict__ B,
                                               const float* __restrict__ bias,
                                               float* __restrict__ C,
                                               int M, int N, int K) {
  __shared__ float As[16][132];
  __shared__ float Bs[16][128];
  const int t = threadIdx.x;
  const int m0 = blockIdx.y * 128, n0 = blockIdx.x * 128;
  const int tx = t & 15, ty = t >> 4;
  const int k4 = t & 3, ra = t >> 2;
  const int nn4 = t & 31, kb = t >> 5;
  float acc[8][8] = {};
  for (int k0 = 0; k0 < K; k0 += 16) {
    const float4 a0 = *(const float4*)(A + (size_t)(m0 + ra) * K + k0 + 4 * k4);
    const float4 a1 = *(const float4*)(A + (size_t)(m0 + ra + 64) * K + k0 + 4 * k4);
    const float4 b0 = *(const float4*)(B + (size_t)(k0 + kb) * N + n0 + 4 * nn4);
    const float4 b1 = *(const float4*)(B + (size_t)(k0 + kb + 8) * N + n0 + 4 * nn4);
    __syncthreads();
    As[4 * k4 + 0][ra] = a0.x; As[4 * k4 + 1][ra] = a0.y;
    As[4 * k4 + 2][ra] = a0.z; As[4 * k4 + 3][ra] = a0.w;
    As[4 * k4 + 0][ra + 64] = a1.x; As[4 * k4 + 1][ra + 64] = a1.y;
    As[4 * k4 + 2][ra + 64] = a1.z; As[4 * k4 + 3][ra + 64] = a1.w;
    *(float4*)&Bs[kb][4 * nn4] = b0;
    *(float4*)&Bs[kb + 8][4 * nn4] = b1;
    __syncthreads();
#pragma unroll
    for (int k = 0; k < 16; ++k) {
      const float4 al = *(const float4*)&As[k][4 * ty];
      const float4 ah2 = *(const float4*)&As[k][64 + 4 * ty];
      const float4 bl = *(const float4*)&Bs[k][4 * tx];
      const float4 bh = *(const float4*)&Bs[k][64 + 4 * tx];
      const float ar[8] = {al.x, al.y, al.z, al.w, ah2.x, ah2.y, ah2.z, ah2.w};
      const float br[8] = {bl.x, bl.y, bl.z, bl.w, bh.x, bh.y, bh.z, bh.w};
#pragma unroll
      for (int ii = 0; ii < 8; ++ii)
#pragma unroll
        for (int jj = 0; jj < 8; ++jj) acc[ii][jj] += ar[ii] * br[jj];
    }
  }
  float bv[8];
#pragma unroll
  for (int jj = 0; jj < 8; ++jj) {
    const int n = n0 + ((jj < 4) ? 4 * tx + jj : 64 + 4 * tx + jj - 4);
    bv[jj] = bias ? bias[n] : 0.f;
  }
#pragma unroll
  for (int ii = 0; ii < 8; ++ii) {
    const int m = m0 + ((ii < 4) ? 4 * ty + ii : 64 + 4 * ty + ii - 4);
    float o[8];
#pragma unroll
    for (int jj = 0; jj < 8; ++jj) {
      float vv = acc[ii][jj] + bv[jj];
      if (ACT == 1) vv = sigmoidf_(vv);
      o[jj] = vv;
    }
    *(float4*)(C + (size_t)m * N + n0 + 4 * tx) = make_float4(o[0], o[1], o[2], o[3]);
    *(float4*)(C + (size_t)m * N + n0 + 64 + 4 * tx) = make_float4(o[4], o[5], o[6], o[7]);
  }
}

// ---------------- attention scores: scale*q.k^T + bias ----------------
__global__ __launch_bounds__(256) void scores_kernel(const float* __restrict__ q,
                                                     const float* __restrict__ k,
                                                     const bf16* __restrict__ bias_all,
                                                     float* __restrict__ scores, int blk) {
  __shared__ float qs[64][49];
  __shared__ float ks[64][49];
  const int t = threadIdx.x;
  const int h = blockIdx.z, i0 = blockIdx.y * 64, j0 = blockIdx.x * 64;
  for (int f = t; f < 64 * 12; f += 256) {
    const int r = f / 12, c4 = f % 12;
    const float4 qv = *(const float4*)(q + (size_t)(i0 + r) * CA + h * DH + 4 * c4);
    qs[r][4 * c4 + 0] = qv.x; qs[r][4 * c4 + 1] = qv.y;
    qs[r][4 * c4 + 2] = qv.z; qs[r][4 * c4 + 3] = qv.w;
    const float4 kv = *(const float4*)(k + (size_t)(j0 + r) * CA + h * DH + 4 * c4);
    ks[r][4 * c4 + 0] = kv.x; ks[r][4 * c4 + 1] = kv.y;
    ks[r][4 * c4 + 2] = kv.z; ks[r][4 * c4 + 3] = kv.w;
  }
  __syncthreads();
  const int tx = t & 15, ty = t >> 4;
  float acc[4][4] = {};
  for (int c = 0; c < DH; ++c) {
    float a[4], b[4];
#pragma unroll
    for (int u = 0; u < 4; ++u) a[u] = qs[4 * ty + u][c];
#pragma unroll
    for (int u = 0; u < 4; ++u) b[u] = ks[4 * tx + u][c];
#pragma unroll
    for (int ii = 0; ii < 4; ++ii)
#pragma unroll
      for (int jj = 0; jj < 4; ++jj) acc[ii][jj] += a[ii] * b[jj];
  }
  const float scale = 0.14433756729740643f;  // 1/sqrt(48)
  const size_t colbase = (size_t)(blk * NHEAD + h) * S * S;
#pragma unroll
  for (int ii = 0; ii < 4; ++ii) {
    const int i = i0 + 4 * ty + ii;
    const bf16* bp = bias_all + colbase + (size_t)i * S + j0 + 4 * tx;
    float4 o;
    o.x = acc[ii][0] * scale + __bfloat162float(bp[0]);
    o.y = acc[ii][1] * scale + __bfloat162float(bp[1]);
    o.z = acc[ii][2] * scale + __bfloat162float(bp[2]);
    o.w = acc[ii][3] * scale + __bfloat162float(bp[3]);
    *(float4*)(scores + (size_t)h * S * S + (size_t)i * S + j0 + 4 * tx) = o;
  }
}

// ---------------- softmax over last dim (1024), in-place ----------------
__global__ __launch_bounds__(256) void softmax_rows(float* __restrict__ scores) {
  __shared__ float red[4];
  const size_t row = blockIdx.x;
  float4* rp = (float4*)(scores + row * S);
  float4 v = rp[threadIdx.x];
  float mx = fmaxf(fmaxf(v.x, v.y), fmaxf(v.z, v.w));
  mx = wred_max(mx);
  const int w = threadIdx.x >> 6;
  if ((threadIdx.x & 63) == 0) red[w] = mx;
  __syncthreads();
  mx = fmaxf(fmaxf(red[0], red[1]), fmaxf(red[2], red[3]));
  v.x = __expf(v.x - mx); v.y = __expf(v.y - mx);
  v.z = __expf(v.z - mx); v.w = __expf(v.w - mx);
  float s = v.x + v.y + v.z + v.w;
  s = wred_sum(s);
  __syncthreads();
  if ((threadIdx.x & 63) == 0) red[w] = s;
  __syncthreads();
  s = red[0] + red[1] + red[2] + red[3];
  const float inv = 1.0f / s;
  v.x *= inv; v.y *= inv; v.z *= inv; v.w *= inv;
  rp[threadIdx.x] = v;
}

// ---------------- o = attn @ v (per head) ----------------
__global__ __launch_bounds__(256) void attnv_kernel(const float* __restrict__ scores,
                                                    const float* __restrict__ v,
                                                    float* __restrict__ o) {
  __shared__ float Ps[64][68];
  __shared__ float Vs[64][52];
  const int t = threadIdx.x;
  const int i0 = blockIdx.x * 64, h = blockIdx.y;
  const int il = t >> 2, dg = t & 3;
  float acc[12] = {};
  for (int j0 = 0; j0 < S; j0 += 64) {
    __syncthreads();
    {
      const int j4 = t & 15;
      for (int ii = t >> 4; ii < 64; ii += 16)
        *(float4*)&Ps[ii][4 * j4] =
            *(const float4*)(scores + (size_t)h * S * S + (size_t)(i0 + ii) * S + j0 + 4 * j4);
      for (int f = t; f < 64 * 12; f += 256) {
        const int j = f / 12, c4 = f % 12;
        *(float4*)&Vs[j][4 * c4] = *(const float4*)(v + (size_t)(j0 + j) * CA + h * DH + 4 * c4);
      }
    }
    __syncthreads();
    for (int j = 0; j < 64; ++j) {
      const float p = Ps[il][j];
#pragma unroll
      for (int d = 0; d < 12; ++d) acc[d] += p * Vs[j][dg * 12 + d];
    }
  }
  float* op = o + (size_t)(i0 + il) * CA + h * DH + dg * 12;
  *(float4*)(op) = make_float4(acc[0], acc[1], acc[2], acc[3]);
  *(float4*)(op + 4) = make_float4(acc[4], acc[5], acc[6], acc[7]);
  *(float4*)(op + 8) = make_float4(acc[8], acc[9], acc[10], acc[11]);
}

// ---------------- elementwise ----------------
__global__ __launch_bounds__(256) void ew_colscale(const float* __restrict__ x,
                                                   const float* __restrict__ w,
                                                   float* __restrict__ out, int n4, int c4) {
  const int i = blockIdx.x * 256 + threadIdx.x;
  if (i >= n4) return;
  const float4 xv = ((const float4*)x)[i];
  const float4 wv = ((const float4*)w)[i % c4];
  ((float4*)out)[i] = make_float4(xv.x * wv.x, xv.y * wv.y, xv.z * wv.z, xv.w * wv.w);
}

__global__ __launch_bounds__(256) void ew_adaln(const float* __restrict__ g,
                                                const float* __restrict__ an,
                                                const float* __restrict__ b,
                                                float* __restrict__ out, int n4) {
  const int i = blockIdx.x * 256 + threadIdx.x;
  if (i >= n4) return;
  const float4 gv = ((const float4*)g)[i];
  const float4 av = ((const float4*)an)[i];
  const float4 bv = ((const float4*)b)[i];
  ((float4*)out)[i] = make_float4(sigmoidf_(gv.x) * av.x + bv.x, sigmoidf_(gv.y) * av.y + bv.y,
                                  sigmoidf_(gv.z) * av.z + bv.z, sigmoidf_(gv.w) * av.w + bv.w);
}

__global__ __launch_bounds__(256) void ew_mul(const float* __restrict__ x,
                                              const float* __restrict__ y,
                                              float* __restrict__ out, int n4) {
  const int i = blockIdx.x * 256 + threadIdx.x;
  if (i >= n4) return;
  const float4 xv = ((const float4*)x)[i];
  const float4 yv = ((const float4*)y)[i];
  ((float4*)out)[i] = make_float4(xv.x * yv.x, xv.y * yv.y, xv.z * yv.z, xv.w * yv.w);
}

__global__ __launch_bounds__(256) void ew_swiglu(const float* __restrict__ x,
                                                 const float* __restrict__ y,
                                                 float* __restrict__ out, int n4) {
  const int i = blockIdx.x * 256 + threadIdx.x;
  if (i >= n4) return;
  const float4 xv = ((const float4*)x)[i];
  const float4 yv = ((const float4*)y)[i];
  ((float4*)out)[i] = make_float4(xv.x * sigmoidf_(xv.x) * yv.x, xv.y * sigmoidf_(xv.y) * yv.y,
                                  xv.z * sigmoidf_(xv.z) * yv.z, xv.w * sigmoidf_(xv.w) * yv.w);
}

__global__ __launch_bounds__(256) void ew_muladd(const float* __restrict__ x,
                                                 const float* __restrict__ y,
                                                 const float* __restrict__ add,
                                                 float* __restrict__ out, int n4) {
  const int i = blockIdx.x * 256 + threadIdx.x;
  if (i >= n4) return;
  const float4 xv = ((const float4*)x)[i];
  const float4 yv = ((const float4*)y)[i];
  const float4 av = ((const float4*)add)[i];
  ((float4*)out)[i] = make_float4(xv.x * yv.x + av.x, xv.y * yv.y + av.y,
                                  xv.z * yv.z + av.z, xv.w * yv.w + av.w);
}

__global__ void fill_kernel(float* p, int n, float v) {
  const int i = blockIdx.x * 256 + threadIdx.x;
  if (i < n) p[i] = v;
}

extern "C" void kernel_launch(void* const* d_in, const int* in_sizes, int n_in,
                              void* d_out, int out_size, void* d_ws, size_t ws_size,
                              hipStream_t stream) {
  (void)in_sizes; (void)n_in;
  const float* a_in = (const float*)d_in[0];
  const float* s_in = (const float*)d_in[1];
  const float* z_in = (const float*)d_in[2];
  const float* beta = (const float*)d_in[3];
  const float* ln_s_w_attn = (const float*)d_in[4];
  const float* wg_attn = (const float*)d_in[5];
  const float* wb_attn = (const float*)d_in[6];
  const float* wq = (const float*)d_in[7];
  const float* bq = (const float*)d_in[8];
  const float* wk = (const float*)d_in[9];
  const float* wv = (const float*)d_in[10];
  const float* ln_z_w = (const float*)d_in[11];
  const float* ln_z_b = (const float*)d_in[12];
  const float* wpb = (const float*)d_in[13];
  const float* wgate = (const float*)d_in[14];
  const float* wo = (const float*)d_in[15];
  const float* wsg_attn = (const float*)d_in[16];
  const float* bsg_attn = (const float*)d_in[17];
  const float* ln_s_w_tr = (const float*)d_in[18];
  const float* wg_tr = (const float*)d_in[19];
  const float* wb_tr = (const float*)d_in[20];
  const float* w_swish = (const float*)d_in[21];
  const float* w_gate2 = (const float*)d_in[22];
  const float* wsg_tr = (const float*)d_in[23];
  const float* bsg_tr = (const float*)d_in[24];
  const float* w_out = (const float*)d_in[25];

  char* wp = (char*)d_ws;
  size_t used = 0;
  auto alloc = [&](size_t bytes) -> void* {
    void* p = wp + used;
    used += (bytes + 255) & ~(size_t)255;
    return p;
  };
  bf16* bias_all = (bf16*)alloc((size_t)64 * S * S * sizeof(bf16));
  float* W2 = (float*)alloc((size_t)CZ * 64 * 4);
  float* bias2 = (float*)alloc(64 * 4);
  float* s_hat = (float*)alloc((size_t)S * CS * 4);
  float* a_buf = (float*)alloc((size_t)S * CA * 4);
  float* a_n = (float*)alloc((size_t)S * CA * 4);
  float* sn = (float*)alloc((size_t)S * CS * 4);
  float* t1 = (float*)alloc((size_t)S * NHID * 4);
  float* t2 = (float*)alloc((size_t)S * NHID * 4);
  float* ah = (float*)alloc((size_t)S * CA * 4);
  float* qb = (float*)alloc((size_t)S * CA * 4);
  float* kb = (float*)alloc((size_t)S * CA * 4);
  float* vb = (float*)alloc((size_t)S * CA * 4);
  float* ob = (float*)alloc((size_t)S * CA * 4);
  float* att = (float*)alloc((size_t)S * CA * 4);
  float* battn = (float*)alloc((size_t)S * CA * 4);
  float* hid = (float*)alloc((size_t)S * NHID * 4);
  float* sc = (float*)alloc((size_t)NHEAD * S * S * 4);
  if (used > ws_size) {
    // distinctive sentinel so a ws shortfall is diagnosable from absmax
    fill_kernel<<<(out_size + 255) / 256, 256, 0, stream>>>((float*)d_out, out_size, 12345.0f);
    return;
  }

  const dim3 blk256(256);
  const dim3 gemm_ca(CA / 128, S / 128);
  const dim3 gemm_nh(NHID / 128, S / 128);
  const int n4_ca = S * CA / 4, n4_cs = S * CS / 4, n4_nh = S * NHID / 4;

  prep_w2<<<1, blk256, 0, stream>>>(ln_z_w, ln_z_b, wpb, W2, bias2);
  rowln_kernel<CS><<<S, blk256, 0, stream>>>(s_in, nullptr, s_hat);
  zbias_kernel<<<dim3(16, 1024), blk256, 0, stream>>>(z_in, beta, W2, bias2, bias_all);

  const float* a_cur = a_in;
  for (int b = 0; b < NBLK; ++b) {
    const size_t oCS = (size_t)b * CS * CA, oCA = (size_t)b * CA * CA;
    const size_t oNH = (size_t)b * CA * NHID, oOUT = (size_t)b * NHID * CA;
    rowln_kernel<CA><<<S, blk256, 0, stream>>>(a_cur, nullptr, a_n);
    // --- AttentionPairBias ---
    ew_colscale<<<n4_cs / 256, blk256, 0, stream>>>(s_hat, ln_s_w_attn + b * CS, sn, n4_cs, CS / 4);
    gemm128<0><<<gemm_ca, blk256, 0, stream>>>(sn, wg_attn + oCS, nullptr, t1, S, CA, CS);
    gemm128<0><<<gemm_ca, blk256, 0, stream>>>(sn, wb_attn + oCS, nullptr, t2, S, CA, CS);
    ew_adaln<<<n4_ca / 256, blk256, 0, stream>>>(t1, a_n, t2, ah, n4_ca);
    gemm128<0><<<gemm_ca, blk256, 0, stream>>>(ah, wq + oCA, bq + b * CA, qb, S, CA, CA);
    gemm128<0><<<gemm_ca, blk256, 0, stream>>>(ah, wk + oCA, nullptr, kb, S, CA, CA);
    gemm128<0><<<gemm_ca, blk256, 0, stream>>>(ah, wv + oCA, nullptr, vb, S, CA, CA);
    scores_kernel<<<dim3(16, 16, 16), blk256, 0, stream>>>(qb, kb, bias_all, sc, b);
    softmax_rows<<<NHEAD * S, blk256, 0, stream>>>(sc);
    attnv_kernel<<<dim3(16, 16), blk256, 0, stream>>>(sc, vb, ob);
    gemm128<1><<<gemm_ca, blk256, 0, stream>>>(ah, wgate + oCA, nullptr, t1, S, CA, CA);
    ew_mul<<<n4_ca / 256, blk256, 0, stream>>>(t1, ob, t2, n4_ca);
    gemm128<0><<<gemm_ca, blk256, 0, stream>>>(t2, wo + oCA, nullptr, att, S, CA, CA);
    gemm128<1><<<gemm_ca, blk256, 0, stream>>>(s_in, wsg_attn + oCS, bsg_attn + b * CA, t1, S, CA, CS);
    ew_mul<<<n4_ca / 256, blk256, 0, stream>>>(t1, att, battn, n4_ca);
    // --- ConditionedTransitionBlock ---
    ew_colscale<<<n4_cs / 256, blk256, 0, stream>>>(s_hat, ln_s_w_tr + b * CS, sn, n4_cs, CS / 4);
    gemm128<0><<<gemm_ca, blk256, 0, stream>>>(sn, wg_tr + oCS, nullptr, t1, S, CA, CS);
    gemm128<0><<<gemm_ca, blk256, 0, stream>>>(sn, wb_tr + oCS, nullptr, t2, S, CA, CS);
    ew_adaln<<<n4_ca / 256, blk256, 0, stream>>>(t1, a_n, t2, ah, n4_ca);
    gemm128<0><<<gemm_nh, blk256, 0, stream>>>(ah, w_swish + oNH, nullptr, t1, S, NHID, CA);
    gemm128<0><<<gemm_nh, blk256, 0, stream>>>(ah, w_gate2 + oNH, nullptr, t2, S, NHID, CA);
    ew_swiglu<<<n4_nh / 256, blk256, 0, stream>>>(t1, t2, hid, n4_nh);
    gemm128<0><<<gemm_ca, blk256, 0, stream>>>(hid, w_out + oOUT, nullptr, qb, S, CA, NHID);
    gemm128<1><<<gemm_ca, blk256, 0, stream>>>(s_in, wsg_tr + oCS, bsg_tr + b * CA, t1, S, CA, CS);
    float* a_next = (b == NBLK - 1) ? (float*)d_out : a_buf;
    ew_muladd<<<n4_ca / 256, blk256, 0, stream>>>(t1, qb, battn, a_next, n4_ca);
    a_cur = a_next;
  }
}

// Round 2
// 1073.120 us; speedup vs baseline: 5.6930x; 5.6930x over previous
//
#include <hip/hip_runtime.h>
#include <hip/hip_bf16.h>

typedef __hip_bfloat16 bf16;
typedef __attribute__((ext_vector_type(8))) short s8v;   // 8 bf16 = 16B
typedef __attribute__((ext_vector_type(4))) float f4v;

constexpr int S = 1024, CA = 768, CS = 384, CZ = 128, NHID = 1536;
constexpr int NBLK = 4, NHEAD = 16, DH = 48;
constexpr float EPS = 1e-5f;

#define DEV static __device__ __forceinline__

DEV float sigmoidf_(float x) { return 1.0f / (1.0f + __expf(-x)); }

DEV f4v mfma16(s8v a, s8v b, f4v c) {
  return __builtin_amdgcn_mfma_f32_16x16x32_bf16(a, b, c, 0, 0, 0);
}

union U8 { s8v s; bf16 h[8]; };

DEV void ld8(const bf16* p, float* o) {
  U8 u; u.s = *(const s8v*)p;
#pragma unroll
  for (int j = 0; j < 8; ++j) o[j] = __bfloat162float(u.h[j]);
}
DEV void st8(bf16* p, const float* o) {
  U8 u;
#pragma unroll
  for (int j = 0; j < 8; ++j) u.h[j] = __float2bfloat16(o[j]);
  *(s8v*)p = u.s;
}

DEV float wred_max(float v) {
#pragma unroll
  for (int o = 32; o; o >>= 1) v = fmaxf(v, __shfl_xor(v, o));
  return v;
}
DEV float wred_sum(float v) {
#pragma unroll
  for (int o = 32; o; o >>= 1) v += __shfl_xor(v, o);
  return v;
}

// ---------------- row LayerNorm -> bf16 ----------------
template <int C>
__global__ __launch_bounds__(256) void rowln_kernel(const float* __restrict__ x,
                                                    bf16* __restrict__ out) {
  constexpr int C4 = C / 4;
  __shared__ float red[8];
  const int t = threadIdx.x;
  const size_t row = blockIdx.x;
  const float4* xr = (const float4*)(x + row * C);
  float4 v = make_float4(0.f, 0.f, 0.f, 0.f);
  if (t < C4) v = xr[t];
  float sum = v.x + v.y + v.z + v.w;
  float sq = v.x * v.x + v.y * v.y + v.z * v.z + v.w * v.w;
  sum = wred_sum(sum);
  sq = wred_sum(sq);
  const int wv = t >> 6;
  if ((t & 63) == 0) { red[2 * wv] = sum; red[2 * wv + 1] = sq; }
  __syncthreads();
  sum = red[0] + red[2] + red[4] + red[6];
  sq = red[1] + red[3] + red[5] + red[7];
  const float m = sum / C;
  const float rstd = rsqrtf(sq / C - m * m + EPS);
  if (t < C4) {
    bf16* op = out + row * C + 4 * t;
    op[0] = __float2bfloat16((v.x - m) * rstd);
    op[1] = __float2bfloat16((v.y - m) * rstd);
    op[2] = __float2bfloat16((v.z - m) * rstd);
    op[3] = __float2bfloat16((v.w - m) * rstd);
  }
}

// ---------------- f32 -> bf16 cast ----------------
__global__ __launch_bounds__(256) void cvt_bf16(const float* __restrict__ x,
                                                bf16* __restrict__ out, int n8) {
  const int i = blockIdx.x * 256 + threadIdx.x;
  if (i >= n8) return;
  const float4 a = ((const float4*)x)[2 * i], b = ((const float4*)x)[2 * i + 1];
  float o[8] = {a.x, a.y, a.z, a.w, b.x, b.y, b.z, b.w};
  st8(out + 8 * i, o);
}

// ---------------- transpose+cvt weights: dst[n][k] = src[k][n] * cs[k] ----------------
__global__ __launch_bounds__(256) void transpose_cvt(const float* __restrict__ src,
                                                     bf16* __restrict__ dst, int K, int N,
                                                     const float* __restrict__ colscale,
                                                     size_t srcZ, size_t dstZ, int csZ) {
  __shared__ float tile[32][33];
  const int z = blockIdx.z;
  src += (size_t)z * srcZ;
  dst += (size_t)z * dstZ;
  const int k0 = blockIdx.y * 32, n0 = blockIdx.x * 32;
  const int tx = threadIdx.x & 31, ty = threadIdx.x >> 5;
#pragma unroll
  for (int q = 0; q < 4; ++q) {
    const int k = k0 + ty + 8 * q;
    float v = src[(size_t)k * N + n0 + tx];
    if (colscale) v *= colscale[(size_t)z * csZ + k];
    tile[ty + 8 * q][tx] = v;
  }
  __syncthreads();
#pragma unroll
  for (int q = 0; q < 4; ++q)
    dst[(size_t)(n0 + ty + 8 * q) * K + k0 + tx] = __float2bfloat16(tile[tx][ty + 8 * q]);
}

// ---------------- bf16 transpose (vT) ----------------
__global__ __launch_bounds__(256) void transpose_bf(const bf16* __restrict__ src, int lds_,
                                                    bf16* __restrict__ dst, int ldd) {
  __shared__ bf16 tile[32][33];
  const int n0 = blockIdx.x * 32, r0 = blockIdx.y * 32;
  const int tx = threadIdx.x & 31, ty = threadIdx.x >> 5;
#pragma unroll
  for (int q = 0; q < 4; ++q)
    tile[ty + 8 * q][tx] = src[(size_t)(r0 + ty + 8 * q) * lds_ + n0 + tx];
  __syncthreads();
#pragma unroll
  for (int q = 0; q < 4; ++q)
    dst[(size_t)(n0 + ty + 8 * q) * ldd + r0 + tx] = tile[tx][ty + 8 * q];
}

// ---------------- prep: W2T bf16 [64][128], bias2 f32[64] ----------------
__global__ __launch_bounds__(256) void prep_w2(const float* __restrict__ ln_z_w,
                                               const float* __restrict__ ln_z_b,
                                               const float* __restrict__ wpb,
                                               bf16* __restrict__ W2T,
                                               float* __restrict__ bias2) {
  const int t = threadIdx.x;
  for (int f = t; f < 64 * CZ; f += 256) {
    const int col = f >> 7, c = f & 127, blk = col >> 4, h = col & 15;
    W2T[f] = __float2bfloat16(ln_z_w[blk * CZ + c] * wpb[(blk * CZ + c) * NHEAD + h]);
  }
  if (t < 64) {
    const int blk = t >> 4, h = t & 15;
    float sum = 0.f;
    for (int c = 0; c < CZ; ++c)
      sum += ln_z_b[blk * CZ + c] * wpb[(blk * CZ + c) * NHEAD + h];
    bias2[t] = sum;
  }
}

// ---------------- prep biases ----------------
__global__ __launch_bounds__(256) void prep_biases(const float* __restrict__ bq,
                                                   const float* __restrict__ bsg_attn,
                                                   const float* __restrict__ bsg_tr,
                                                   float* __restrict__ biasQKVG,
                                                   float* __restrict__ biasSG) {
  const int t = blockIdx.x * 256 + threadIdx.x;
  if (t < 4 * 3072) {
    const int b = t / 3072, c = t % 3072;
    biasQKVG[t] = (c < 768) ? bq[b * 768 + c] : 0.f;
  }
  if (t < 6144) {
    const int b = t / 1536, c = t % 1536;
    biasSG[t] = (c < 768) ? bsg_attn[b * 768 + c] : bsg_tr[b * 768 + c - 768];
  }
}

// ---------------- zbias: LN(z)@W2T + bias2 + beta -> bf16 [64][S][S], MFMA ----------------
__global__ __launch_bounds__(256) void zbias_kernel(const float* __restrict__ z,
                                                    const float* __restrict__ beta,
                                                    const bf16* __restrict__ W2T,
                                                    const float* __restrict__ bias2,
                                                    bf16* __restrict__ bias_all) {
  __shared__ s8v zt8[64 * 16];
  __shared__ s8v w2s[64 * 16];
  __shared__ float betas[64][17];
  __shared__ float bias2s[64];
  const int t = threadIdx.x;
  const int i = blockIdx.y, j0 = blockIdx.x * 64;
  // stage W2T swizzled
#pragma unroll
  for (int q = 0; q < 4; ++q) {
    const int u = q * 256 + t;           // 16B unit: 64 rows x 16 slots
    const int row = u >> 4, sl = u & 15;
    w2s[row * 16 + (sl ^ (row & 7))] = *(const s8v*)(W2T + row * CZ + sl * 8);
  }
  if (t < 64) bias2s[t] = bias2[t];
  {
    const int j = t >> 2, h4 = t & 3;
    const float4 bv = *(const float4*)(beta + ((size_t)i * S + j0 + j) * NHEAD + 4 * h4);
    betas[j][4 * h4 + 0] = bv.x; betas[j][4 * h4 + 1] = bv.y;
    betas[j][4 * h4 + 2] = bv.z; betas[j][4 * h4 + 3] = bv.w;
  }
  // LN of 64 z rows -> zt8 (swizzled bf16)
  {
    const int p = t >> 2, q = t & 3;
    const float* zr = z + ((size_t)i * S + j0 + p) * CZ + q * 32;
    float vals[32];
    float sum = 0.f, sq = 0.f;
#pragma unroll
    for (int k4 = 0; k4 < 8; ++k4) {
      const float4 xv = *(const float4*)(zr + 4 * k4);
      vals[4 * k4 + 0] = xv.x; vals[4 * k4 + 1] = xv.y;
      vals[4 * k4 + 2] = xv.z; vals[4 * k4 + 3] = xv.w;
      sum += xv.x + xv.y + xv.z + xv.w;
      sq += xv.x * xv.x + xv.y * xv.y + xv.z * xv.z + xv.w * xv.w;
    }
    sum += __shfl_xor(sum, 1); sum += __shfl_xor(sum, 2);
    sq += __shfl_xor(sq, 1); sq += __shfl_xor(sq, 2);
    const float m = sum / CZ;
    const float rstd = rsqrtf(sq / CZ - m * m + EPS);
    bf16* ztb = (bf16*)zt8;
#pragma unroll
    for (int c0 = 0; c0 < 32; ++c0) {
      const int c = q * 32 + c0;
      const int phys = (c >> 3) ^ (p & 7);
      ztb[p * 128 + phys * 8 + (c & 7)] = __float2bfloat16((vals[c0] - m) * rstd);
    }
  }
  __syncthreads();
  const int lane = t & 63, wid = t >> 6;
  const int wr = wid >> 1, wc = wid & 1;
  const int ln = lane & 15, lq = lane >> 4;
  f4v acc[2][2] = {};
#pragma unroll
  for (int kk = 0; kk < 4; ++kk) {
    const int sl = (lq + 4 * kk) ^ (ln & 7);
    s8v a[2], b[2];
#pragma unroll
    for (int mi = 0; mi < 2; ++mi) a[mi] = zt8[(32 * wr + 16 * mi + ln) * 16 + sl];
#pragma unroll
    for (int ni = 0; ni < 2; ++ni) b[ni] = w2s[(32 * wc + 16 * ni + ln) * 16 + sl];
#pragma unroll
    for (int mi = 0; mi < 2; ++mi)
#pragma unroll
      for (int ni = 0; ni < 2; ++ni) acc[mi][ni] = mfma16(a[mi], b[ni], acc[mi][ni]);
  }
#pragma unroll
  for (int mi = 0; mi < 2; ++mi)
#pragma unroll
    for (int ni = 0; ni < 2; ++ni) {
      const int col = 32 * wc + 16 * ni + ln;
#pragma unroll
      for (int r = 0; r < 4; ++r) {
        const int j = 32 * wr + 16 * mi + 4 * lq + r;
        const float val = acc[mi][ni][r] + bias2s[col] + betas[j][col & 15];
        bias_all[(size_t)col * S * S + (size_t)i * S + j0 + j] = __float2bfloat16(val);
      }
    }
}

// ---------------- MFMA GEMM: C[M][N] = act(A[M][K] @ Bt[N][K]^T + bias) ----------------
// 128x128 tile, BK=64, 256 threads (4 waves 2x2), swizzled LDS, bf16 out
template <int ACT>
__global__ __launch_bounds__(256) void gemm_nt(const bf16* __restrict__ A,
                                               const bf16* __restrict__ Bt,
                                               const float* __restrict__ bias,
                                               bf16* __restrict__ C, int M, int N, int K) {
  __shared__ s8v As[128 * 8];
  __shared__ s8v Bs[128 * 8];
  const int t = threadIdx.x;
  const int lane = t & 63, wid = t >> 6;
  const int wr = wid >> 1, wc = wid & 1;
  const int ln = lane & 15, lq = lane >> 4;
  const int m0 = blockIdx.y * 128, n0 = blockIdx.x * 128;
  int rowS[4], slS[4], swz[4];
#pragma unroll
  for (int q = 0; q < 4; ++q) {
    const int u = q * 256 + t;
    rowS[q] = u >> 3; slS[q] = u & 7;
    swz[q] = rowS[q] * 8 + (slS[q] ^ (rowS[q] & 7));
  }
  f4v acc[4][4] = {};
  s8v ra[4], rb[4];
#pragma unroll
  for (int q = 0; q < 4; ++q) {
    ra[q] = *(const s8v*)(A + (size_t)(m0 + rowS[q]) * K + slS[q] * 8);
    rb[q] = *(const s8v*)(Bt + (size_t)(n0 + rowS[q]) * K + slS[q] * 8);
  }
  for (int ks = 0;;) {
    __syncthreads();
#pragma unroll
    for (int q = 0; q < 4; ++q) { As[swz[q]] = ra[q]; Bs[swz[q]] = rb[q]; }
    const int ksn = ks + 64;
    if (ksn < K) {
#pragma unroll
      for (int q = 0; q < 4; ++q) {
        ra[q] = *(const s8v*)(A + (size_t)(m0 + rowS[q]) * K + ksn + slS[q] * 8);
        rb[q] = *(const s8v*)(Bt + (size_t)(n0 + rowS[q]) * K + ksn + slS[q] * 8);
      }
    }
    __syncthreads();
#pragma unroll
    for (int kk = 0; kk < 2; ++kk) {
      const int sl = (lq + 4 * kk) ^ (ln & 7);
      s8v a[4], b[4];
#pragma unroll
      for (int mi = 0; mi < 4; ++mi) a[mi] = As[(64 * wr + 16 * mi + ln) * 8 + sl];
#pragma unroll
      for (int ni = 0; ni < 4; ++ni) b[ni] = Bs[(64 * wc + 16 * ni + ln) * 8 + sl];
#pragma unroll
      for (int mi = 0; mi < 4; ++mi)
#pragma unroll
        for (int ni = 0; ni < 4; ++ni) acc[mi][ni] = mfma16(a[mi], b[ni], acc[mi][ni]);
    }
    ks = ksn;
    if (ks >= K) break;
  }
#pragma unroll
  for (int ni = 0; ni < 4; ++ni) {
    const int n = n0 + 64 * wc + 16 * ni + ln;
    const float bv = bias ? bias[n] : 0.f;
#pragma unroll
    for (int mi = 0; mi < 4; ++mi) {
      const int mb = m0 + 64 * wr + 16 * mi + 4 * lq;
#pragma unroll
      for (int r = 0; r < 4; ++r) {
        float v = acc[mi][ni][r] + bv;
        if (ACT == 1) v = sigmoidf_(v);
        C[(size_t)(mb + r) * N + n] = __float2bfloat16(v);
      }
    }
  }
}

// ---------------- scores: scale*q.kT + bias -> f32 [16][S][S] ----------------
__global__ __launch_bounds__(256) void scores_mfma(const bf16* __restrict__ q,
                                                   const bf16* __restrict__ k,
                                                   const bf16* __restrict__ bias_all,
                                                   float* __restrict__ sc, int blk) {
  __shared__ s8v Qs[128 * 8];
  __shared__ s8v Ks[128 * 8];
  const int t = threadIdx.x;
  const int lane = t & 63, wid = t >> 6;
  const int wr = wid >> 1, wc = wid & 1;
  const int ln = lane & 15, lq = lane >> 4;
  const int h = blockIdx.z, i0 = blockIdx.y * 128, j0 = blockIdx.x * 128;
#pragma unroll
  for (int q4 = 0; q4 < 4; ++q4) {
    const int u = q4 * 256 + t;
    const int row = u >> 3, sl = u & 7;
    s8v zero{};
    s8v qv = (sl < 6) ? *(const s8v*)(q + (size_t)(i0 + row) * 3072 + h * DH + sl * 8) : zero;
    s8v kv = (sl < 6) ? *(const s8v*)(k + (size_t)(j0 + row) * 3072 + h * DH + sl * 8) : zero;
    Qs[row * 8 + (sl ^ (row & 7))] = qv;
    Ks[row * 8 + (sl ^ (row & 7))] = kv;
  }
  __syncthreads();
  f4v acc[4][4] = {};
#pragma unroll
  for (int kk = 0; kk < 2; ++kk) {
    const int sl = (lq + 4 * kk) ^ (ln & 7);
    s8v a[4], b[4];
#pragma unroll
    for (int mi = 0; mi < 4; ++mi) a[mi] = Qs[(64 * wr + 16 * mi + ln) * 8 + sl];
#pragma unroll
    for (int ni = 0; ni < 4; ++ni) b[ni] = Ks[(64 * wc + 16 * ni + ln) * 8 + sl];
#pragma unroll
    for (int mi = 0; mi < 4; ++mi)
#pragma unroll
      for (int ni = 0; ni < 4; ++ni) acc[mi][ni] = mfma16(a[mi], b[ni], acc[mi][ni]);
  }
  const float scale = 0.14433756729740643f;
  const bf16* bp = bias_all + (size_t)(blk * NHEAD + h) * S * S;
  float* scp = sc + (size_t)h * S * S;
#pragma unroll
  for (int mi = 0; mi < 4; ++mi)
#pragma unroll
    for (int ni = 0; ni < 4; ++ni) {
      const int j = j0 + 64 * wc + 16 * ni + ln;
#pragma unroll
      for (int r = 0; r < 4; ++r) {
        const int i = i0 + 64 * wr + 16 * mi + 4 * lq + r;
        scp[(size_t)i * S + j] =
            acc[mi][ni][r] * scale + __bfloat162float(bp[(size_t)i * S + j]);
      }
    }
}

// ---------------- softmax over last dim (1024), in-place ----------------
__global__ __launch_bounds__(256) void softmax_rows(float* __restrict__ scores) {
  __shared__ float red[4];
  const size_t row = blockIdx.x;
  float4* rp = (float4*)(scores + row * S);
  float4 v = rp[threadIdx.x];
  float mx = fmaxf(fmaxf(v.x, v.y), fmaxf(v.z, v.w));
  mx = wred_max(mx);
  const int w = threadIdx.x >> 6;
  if ((threadIdx.x & 63) == 0) red[w] = mx;
  __syncthreads();
  mx = fmaxf(fmaxf(red[0], red[1]), fmaxf(red[2], red[3]));
  v.x = __expf(v.x - mx); v.y = __expf(v.y - mx);
  v.z = __expf(v.z - mx); v.w = __expf(v.w - mx);
  float s = v.x + v.y + v.z + v.w;
  s = wred_sum(s);
  __syncthreads();
  if ((threadIdx.x & 63) == 0) red[w] = s;
  __syncthreads();
  s = red[0] + red[1] + red[2] + red[3];
  const float inv = 1.0f / s;
  v.x *= inv; v.y *= inv; v.z *= inv; v.w *= inv;
  rp[threadIdx.x] = v;
}

// ---------------- attnV: o = P @ V, MFMA (per head), P f32 cvt on stage ----------------
__global__ __launch_bounds__(256) void attnv_mfma(const float* __restrict__ sc,
                                                  const bf16* __restrict__ vT,
                                                  bf16* __restrict__ ob) {
  __shared__ s8v Ps[128 * 8];
  __shared__ s8v Vs[48 * 8];
  const int t = threadIdx.x;
  const int lane = t & 63, wid = t >> 6;
  const int ln = lane & 15, lq = lane >> 4;
  const int h = blockIdx.y, i0 = blockIdx.x * 128;
  f4v acc[2][3] = {};
  for (int ks = 0; ks < S; ks += 64) {
    __syncthreads();
#pragma unroll
    for (int q4 = 0; q4 < 4; ++q4) {
      const int u = q4 * 256 + t;
      const int row = u >> 3, sl = u & 7;
      const float* sp = sc + (size_t)h * S * S + (size_t)(i0 + row) * S + ks + sl * 8;
      const float4 x0 = *(const float4*)sp, x1 = *(const float4*)(sp + 4);
      U8 uu;
      uu.h[0] = __float2bfloat16(x0.x); uu.h[1] = __float2bfloat16(x0.y);
      uu.h[2] = __float2bfloat16(x0.z); uu.h[3] = __float2bfloat16(x0.w);
      uu.h[4] = __float2bfloat16(x1.x); uu.h[5] = __float2bfloat16(x1.y);
      uu.h[6] = __float2bfloat16(x1.z); uu.h[7] = __float2bfloat16(x1.w);
      Ps[row * 8 + (sl ^ (row & 7))] = uu.s;
    }
    for (int u = t; u < 384; u += 256) {
      const int row = u >> 3, sl = u & 7;
      Vs[row * 8 + (sl ^ (row & 7))] =
          *(const s8v*)(vT + (size_t)(h * DH + row) * S + ks + sl * 8);
    }
    __syncthreads();
#pragma unroll
    for (int kk = 0; kk < 2; ++kk) {
      const int sl = (lq + 4 * kk) ^ (ln & 7);
      s8v a[2], b[3];
#pragma unroll
      for (int mi = 0; mi < 2; ++mi) a[mi] = Ps[(32 * wid + 16 * mi + ln) * 8 + sl];
#pragma unroll
      for (int ni = 0; ni < 3; ++ni) b[ni] = Vs[(16 * ni + ln) * 8 + sl];
#pragma unroll
      for (int mi = 0; mi < 2; ++mi)
#pragma unroll
        for (int ni = 0; ni < 3; ++ni) acc[mi][ni] = mfma16(a[mi], b[ni], acc[mi][ni]);
    }
  }
#pragma unroll
  for (int mi = 0; mi < 2; ++mi)
#pragma unroll
    for (int ni = 0; ni < 3; ++ni) {
      const int d = 16 * ni + ln;
#pragma unroll
      for (int r = 0; r < 4; ++r) {
        const int m = i0 + 32 * wid + 16 * mi + 4 * lq + r;
        ob[(size_t)m * CA + h * DH + d] = __float2bfloat16(acc[mi][ni][r]);
      }
    }
}

// ---------------- elementwise (bf16, 8/thread) ----------------
__global__ __launch_bounds__(256) void ew_adaln(const bf16* __restrict__ g,
                                                const bf16* __restrict__ bb,
                                                const bf16* __restrict__ an,
                                                bf16* __restrict__ out, int ldg) {
  const int c = blockIdx.x * 256 + threadIdx.x;  // 1024*96 chunks
  const int row = c / 96, col = (c % 96) * 8;
  float gv[8], bv[8], av[8], o[8];
  ld8(g + (size_t)row * ldg + col, gv);
  ld8(bb + (size_t)row * ldg + col, bv);
  ld8(an + (size_t)row * CA + col, av);
#pragma unroll
  for (int j = 0; j < 8; ++j) o[j] = sigmoidf_(gv[j]) * av[j] + bv[j];
  st8(out + (size_t)row * CA + col, o);
}

__global__ __launch_bounds__(256) void ew_sigmul(const bf16* __restrict__ x, int ldx,
                                                 const bf16* __restrict__ y,
                                                 bf16* __restrict__ out) {
  const int c = blockIdx.x * 256 + threadIdx.x;
  const int row = c / 96, col = (c % 96) * 8;
  float xv[8], yv[8], o[8];
  ld8(x + (size_t)row * ldx + col, xv);
  ld8(y + (size_t)row * CA + col, yv);
#pragma unroll
  for (int j = 0; j < 8; ++j) o[j] = sigmoidf_(xv[j]) * yv[j];
  st8(out + (size_t)row * CA + col, o);
}

__global__ __launch_bounds__(256) void ew_mul(const bf16* __restrict__ x, int ldx,
                                              const bf16* __restrict__ y,
                                              bf16* __restrict__ out) {
  const int c = blockIdx.x * 256 + threadIdx.x;
  const int row = c / 96, col = (c % 96) * 8;
  float xv[8], yv[8], o[8];
  ld8(x + (size_t)row * ldx + col, xv);
  ld8(y + (size_t)row * CA + col, yv);
#pragma unroll
  for (int j = 0; j < 8; ++j) o[j] = xv[j] * yv[j];
  st8(out + (size_t)row * CA + col, o);
}

__global__ __launch_bounds__(256) void ew_swiglu(const bf16* __restrict__ swg,
                                                 bf16* __restrict__ hid) {
  const int c = blockIdx.x * 256 + threadIdx.x;  // 1024*192 chunks
  const int row = c / 192, col = (c % 192) * 8;
  float xv[8], yv[8], o[8];
  ld8(swg + (size_t)row * 3072 + col, xv);
  ld8(swg + (size_t)row * 3072 + 1536 + col, yv);
#pragma unroll
  for (int j = 0; j < 8; ++j) o[j] = xv[j] * sigmoidf_(xv[j]) * yv[j];
  st8(hid + (size_t)row * 1536 + col, o);
}

__global__ __launch_bounds__(256) void ew_muladd_out(const bf16* __restrict__ x, int ldx,
                                                     const bf16* __restrict__ y,
                                                     const bf16* __restrict__ add,
                                                     float* __restrict__ out) {
  const int c = blockIdx.x * 256 + threadIdx.x;
  const int row = c / 96, col = (c % 96) * 8;
  float xv[8], yv[8], av[8];
  ld8(x + (size_t)row * ldx + col, xv);
  ld8(y + (size_t)row * CA + col, yv);
  ld8(add + (size_t)row * CA + col, av);
  float4 o0, o1;
  o0.x = xv[0] * yv[0] + av[0]; o0.y = xv[1] * yv[1] + av[1];
  o0.z = xv[2] * yv[2] + av[2]; o0.w = xv[3] * yv[3] + av[3];
  o1.x = xv[4] * yv[4] + av[4]; o1.y = xv[5] * yv[5] + av[5];
  o1.z = xv[6] * yv[6] + av[6]; o1.w = xv[7] * yv[7] + av[7];
  float* op = out + (size_t)row * CA + col;
  *(float4*)op = o0;
  *(float4*)(op + 4) = o1;
}

__global__ void fill_kernel(float* p, int n, float v) {
  const int i = blockIdx.x * 256 + threadIdx.x;
  if (i < n) p[i] = v;
}

extern "C" void kernel_launch(void* const* d_in, const int* in_sizes, int n_in,
                              void* d_out, int out_size, void* d_ws, size_t ws_size,
                              hipStream_t stream) {
  (void)in_sizes; (void)n_in;
  const float* a_in = (const float*)d_in[0];
  const float* s_in = (const float*)d_in[1];
  const float* z_in = (const float*)d_in[2];
  const float* beta = (const float*)d_in[3];
  const float* ln_s_w_attn = (const float*)d_in[4];
  const float* wg_attn = (const float*)d_in[5];
  const float* wb_attn = (const float*)d_in[6];
  const float* wq = (const float*)d_in[7];
  const float* bq = (const float*)d_in[8];
  const float* wk = (const float*)d_in[9];
  const float* wv = (const float*)d_in[10];
  const float* ln_z_w = (const float*)d_in[11];
  const float* ln_z_b = (const float*)d_in[12];
  const float* wpb = (const float*)d_in[13];
  const float* wgate = (const float*)d_in[14];
  const float* wo = (const float*)d_in[15];
  const float* wsg_attn = (const float*)d_in[16];
  const float* bsg_attn = (const float*)d_in[17];
  const float* ln_s_w_tr = (const float*)d_in[18];
  const float* wg_tr = (const float*)d_in[19];
  const float* wb_tr = (const float*)d_in[20];
  const float* w_swish = (const float*)d_in[21];
  const float* w_gate2 = (const float*)d_in[22];
  const float* wsg_tr = (const float*)d_in[23];
  const float* bsg_tr = (const float*)d_in[24];
  const float* w_out = (const float*)d_in[25];

  char* wp = (char*)d_ws;
  size_t used = 0;
  auto alloc = [&](size_t bytes) -> void* {
    void* p = wp + used;
    used += (bytes + 255) & ~(size_t)255;
    return p;
  };
  bf16* bias_all = (bf16*)alloc((size_t)64 * S * S * 2);
  float* sc = (float*)alloc((size_t)NHEAD * S * S * 4);
  bf16* WT_ada = (bf16*)alloc((size_t)12288 * 384 * 2);
  bf16* WT_sg = (bf16*)alloc((size_t)6144 * 384 * 2);
  bf16* WT_qkvg = (bf16*)alloc((size_t)4 * 3072 * 768 * 2);
  bf16* WT_wo = (bf16*)alloc((size_t)4 * 768 * 768 * 2);
  bf16* WT_mlp = (bf16*)alloc((size_t)4 * 3072 * 768 * 2);
  bf16* WT_wout = (bf16*)alloc((size_t)4 * 768 * 1536 * 2);
  float* biasQKVG = (float*)alloc(4 * 3072 * 4);
  float* biasSG = (float*)alloc(6144 * 4);
  bf16* W2T = (bf16*)alloc(64 * 128 * 2);
  float* bias2 = (float*)alloc(64 * 4);
  bf16* ada_all = (bf16*)alloc((size_t)S * 12288 * 2);
  bf16* sg_all = (bf16*)alloc((size_t)S * 6144 * 2);
  bf16* s_hat = (bf16*)alloc((size_t)S * CS * 2);
  bf16* s_bf = (bf16*)alloc((size_t)S * CS * 2);
  bf16* a_n = (bf16*)alloc((size_t)S * CA * 2);
  float* a_buf = (float*)alloc((size_t)S * CA * 4);
  bf16* qkvg = (bf16*)alloc((size_t)S * 3072 * 2);
  bf16* vT = (bf16*)alloc((size_t)CA * S * 2);
  bf16* ob = (bf16*)alloc((size_t)S * CA * 2);
  bf16* go = (bf16*)alloc((size_t)S * CA * 2);
  bf16* att = (bf16*)alloc((size_t)S * CA * 2);
  bf16* battn = (bf16*)alloc((size_t)S * CA * 2);
  bf16* ah = (bf16*)alloc((size_t)S * CA * 2);
  bf16* trout = (bf16*)alloc((size_t)S * CA * 2);
  bf16* swg = (bf16*)alloc((size_t)S * 3072 * 2);
  bf16* hid = (bf16*)alloc((size_t)S * 1536 * 2);
  if (used > ws_size) {
    fill_kernel<<<(out_size + 255) / 256, 256, 0, stream>>>((float*)d_out, out_size, 12345.0f);
    return;
  }

  const dim3 B256(256);

  // ---- prep ----
  prep_w2<<<1, B256, 0, stream>>>(ln_z_w, ln_z_b, wpb, W2T, bias2);
  prep_biases<<<48, B256, 0, stream>>>(bq, bsg_attn, bsg_tr, biasQKVG, biasSG);
  // ada weights (ln_s folded), layout per block: [g_attn, b_attn, g_tr, b_tr]
  transpose_cvt<<<dim3(24, 12, 4), B256, 0, stream>>>(wg_attn, WT_ada + (size_t)0 * 384, 384, 768, ln_s_w_attn, (size_t)CS * CA, (size_t)3072 * 384, CS);
  transpose_cvt<<<dim3(24, 12, 4), B256, 0, stream>>>(wb_attn, WT_ada + (size_t)768 * 384, 384, 768, ln_s_w_attn, (size_t)CS * CA, (size_t)3072 * 384, CS);
  transpose_cvt<<<dim3(24, 12, 4), B256, 0, stream>>>(wg_tr, WT_ada + (size_t)1536 * 384, 384, 768, ln_s_w_tr, (size_t)CS * CA, (size_t)3072 * 384, CS);
  transpose_cvt<<<dim3(24, 12, 4), B256, 0, stream>>>(wb_tr, WT_ada + (size_t)2304 * 384, 384, 768, ln_s_w_tr, (size_t)CS * CA, (size_t)3072 * 384, CS);
  transpose_cvt<<<dim3(24, 12, 4), B256, 0, stream>>>(wsg_attn, WT_sg + (size_t)0 * 384, 384, 768, nullptr, (size_t)CS * CA, (size_t)1536 * 384, 0);
  transpose_cvt<<<dim3(24, 12, 4), B256, 0, stream>>>(wsg_tr, WT_sg + (size_t)768 * 384, 384, 768, nullptr, (size_t)CS * CA, (size_t)1536 * 384, 0);
  transpose_cvt<<<dim3(24, 24, 4), B256, 0, stream>>>(wq, WT_qkvg + (size_t)0 * 768, 768, 768, nullptr, (size_t)CA * CA, (size_t)3072 * 768, 0);
  transpose_cvt<<<dim3(24, 24, 4), B256, 0, stream>>>(wk, WT_qkvg + (size_t)768 * 768, 768, 768, nullptr, (size_t)CA * CA, (size_t)3072 * 768, 0);
  transpose_cvt<<<dim3(24, 24, 4), B256, 0, stream>>>(wv, WT_qkvg + (size_t)1536 * 768, 768, 768, nullptr, (size_t)CA * CA, (size_t)3072 * 768, 0);
  transpose_cvt<<<dim3(24, 24, 4), B256, 0, stream>>>(wgate, WT_qkvg + (size_t)2304 * 768, 768, 768, nullptr, (size_t)CA * CA, (size_t)3072 * 768, 0);
  transpose_cvt<<<dim3(24, 24, 4), B256, 0, stream>>>(wo, WT_wo, 768, 768, nullptr, (size_t)CA * CA, (size_t)768 * 768, 0);
  transpose_cvt<<<dim3(48, 24, 4), B256, 0, stream>>>(w_swish, WT_mlp + (size_t)0 * 768, 768, 1536, nullptr, (size_t)CA * NHID, (size_t)3072 * 768, 0);
  transpose_cvt<<<dim3(48, 24, 4), B256, 0, stream>>>(w_gate2, WT_mlp + (size_t)1536 * 768, 768, 1536, nullptr, (size_t)CA * NHID, (size_t)3072 * 768, 0);
  transpose_cvt<<<dim3(24, 48, 4), B256, 0, stream>>>(w_out, WT_wout, 1536, 768, nullptr, (size_t)NHID * CA, (size_t)768 * 1536, 0);

  rowln_kernel<CS><<<S, B256, 0, stream>>>(s_in, s_hat);
  cvt_bf16<<<(S * CS / 8 + 255) / 256, B256, 0, stream>>>(s_in, s_bf, S * CS / 8);
  zbias_kernel<<<dim3(16, 1024), B256, 0, stream>>>(z_in, beta, W2T, bias2, bias_all);

  // hoisted GEMMs
  gemm_nt<0><<<dim3(96, 8), B256, 0, stream>>>(s_hat, WT_ada, nullptr, ada_all, S, 12288, 384);
  gemm_nt<1><<<dim3(48, 8), B256, 0, stream>>>(s_bf, WT_sg, biasSG, sg_all, S, 6144, 384);

  const float* a_cur = a_in;
  for (int b = 0; b < NBLK; ++b) {
    rowln_kernel<CA><<<S, B256, 0, stream>>>(a_cur, a_n);
    // --- AttentionPairBias ---
    ew_adaln<<<384, B256, 0, stream>>>(ada_all + (size_t)b * 3072, ada_all + (size_t)b * 3072 + 768, a_n, ah, 12288);
    gemm_nt<0><<<dim3(24, 8), B256, 0, stream>>>(ah, WT_qkvg + (size_t)b * 3072 * 768, biasQKVG + b * 3072, qkvg, S, 3072, 768);
    transpose_bf<<<dim3(24, 32), B256, 0, stream>>>(qkvg + 1536, 3072, vT, S);
    scores_mfma<<<dim3(8, 8, 16), B256, 0, stream>>>(qkvg, qkvg + 768, bias_all, sc, b);
    softmax_rows<<<NHEAD * S, B256, 0, stream>>>(sc);
    attnv_mfma<<<dim3(8, 16), B256, 0, stream>>>(sc, vT, ob);
    ew_sigmul<<<384, B256, 0, stream>>>(qkvg + 2304, 3072, ob, go);
    gemm_nt<0><<<dim3(6, 8), B256, 0, stream>>>(go, WT_wo + (size_t)b * 768 * 768, nullptr, att, S, 768, 768);
    ew_mul<<<384, B256, 0, stream>>>(sg_all + (size_t)b * 1536, 6144, att, battn);
    // --- ConditionedTransitionBlock ---
    ew_adaln<<<384, B256, 0, stream>>>(ada_all + (size_t)b * 3072 + 1536, ada_all + (size_t)b * 3072 + 2304, a_n, ah, 12288);
    gemm_nt<0><<<dim3(24, 8), B256, 0, stream>>>(ah, WT_mlp + (size_t)b * 3072 * 768, nullptr, swg, S, 3072, 768);
    ew_swiglu<<<768, B256, 0, stream>>>(swg, hid);
    gemm_nt<0><<<dim3(6, 8), B256, 0, stream>>>(hid, WT_wout + (size_t)b * 768 * 1536, nullptr, trout, S, 768, 1536);
    float* a_next = (b == NBLK - 1) ? (float*)d_out : a_buf;
    ew_muladd_out<<<384, B256, 0, stream>>>(sg_all + (size_t)b * 1536 + 768, 6144, trout, battn, a_next);
    a_cur = a_next;
  }
}

// Round 3
// 850.190 us; speedup vs baseline: 7.1858x; 1.2622x over previous
//
#include <hip/hip_runtime.h>
#include <hip/hip_bf16.h>

typedef __hip_bfloat16 bf16;
typedef __attribute__((ext_vector_type(8))) short s8v;   // 8 bf16 = 16B
typedef __attribute__((ext_vector_type(4))) float f4v;

constexpr int S = 1024, CA = 768, CS = 384, CZ = 128, NHID = 1536;
constexpr int NBLK = 4, NHEAD = 16, DH = 48;
constexpr float EPS = 1e-5f;

#define DEV static __device__ __forceinline__

DEV float sigmoidf_(float x) { return 1.0f / (1.0f + __expf(-x)); }

DEV f4v mfma16(s8v a, s8v b, f4v c) {
  return __builtin_amdgcn_mfma_f32_16x16x32_bf16(a, b, c, 0, 0, 0);
}

union U8 { s8v s; bf16 h[8]; };
union U4 { uint2 u; bf16 h[4]; };

DEV void ld8(const bf16* p, float* o) {
  U8 u; u.s = *(const s8v*)p;
#pragma unroll
  for (int j = 0; j < 8; ++j) o[j] = __bfloat162float(u.h[j]);
}

DEV float wred_max(float v) {
#pragma unroll
  for (int o = 32; o; o >>= 1) v = fmaxf(v, __shfl_xor(v, o));
  return v;
}
DEV float wred_sum(float v) {
#pragma unroll
  for (int o = 32; o; o >>= 1) v += __shfl_xor(v, o);
  return v;
}

// ---------------- row LayerNorm -> bf16 (for s) ----------------
template <int C>
__global__ __launch_bounds__(256) void rowln_kernel(const float* __restrict__ x,
                                                    bf16* __restrict__ out) {
  constexpr int C4 = C / 4;
  __shared__ float red[8];
  const int t = threadIdx.x;
  const size_t row = blockIdx.x;
  const float4* xr = (const float4*)(x + row * C);
  float4 v = make_float4(0.f, 0.f, 0.f, 0.f);
  if (t < C4) v = xr[t];
  float sum = v.x + v.y + v.z + v.w;
  float sq = v.x * v.x + v.y * v.y + v.z * v.z + v.w * v.w;
  sum = wred_sum(sum);
  sq = wred_sum(sq);
  const int wv = t >> 6;
  if ((t & 63) == 0) { red[2 * wv] = sum; red[2 * wv + 1] = sq; }
  __syncthreads();
  sum = red[0] + red[2] + red[4] + red[6];
  sq = red[1] + red[3] + red[5] + red[7];
  const float m = sum / C;
  const float rstd = rsqrtf(sq / C - m * m + EPS);
  if (t < C4) {
    bf16* op = out + row * C + 4 * t;
    op[0] = __float2bfloat16((v.x - m) * rstd);
    op[1] = __float2bfloat16((v.y - m) * rstd);
    op[2] = __float2bfloat16((v.z - m) * rstd);
    op[3] = __float2bfloat16((v.w - m) * rstd);
  }
}

// ---------------- fused LN(a) + both adaLNs ----------------
__global__ __launch_bounds__(256) void ln_adaln2(const float* __restrict__ a,
                                                 const bf16* __restrict__ ada, // +b*3072, ld 12288
                                                 bf16* __restrict__ ah_attn,
                                                 bf16* __restrict__ ah_tr) {
  __shared__ float red[8];
  const int t = threadIdx.x;
  const size_t row = blockIdx.x;
  float4 v = make_float4(0.f, 0.f, 0.f, 0.f);
  if (t < 192) v = ((const float4*)(a + row * CA))[t];
  float sum = v.x + v.y + v.z + v.w;
  float sq = v.x * v.x + v.y * v.y + v.z * v.z + v.w * v.w;
  sum = wred_sum(sum);
  sq = wred_sum(sq);
  const int wv = t >> 6;
  if ((t & 63) == 0) { red[2 * wv] = sum; red[2 * wv + 1] = sq; }
  __syncthreads();
  sum = red[0] + red[2] + red[4] + red[6];
  sq = red[1] + red[3] + red[5] + red[7];
  const float m = sum / CA;
  const float rstd = rsqrtf(sq / CA - m * m + EPS);
  if (t < 192) {
    const float an[4] = {(v.x - m) * rstd, (v.y - m) * rstd, (v.z - m) * rstd, (v.w - m) * rstd};
    const bf16* ar = ada + row * 12288 + 4 * t;
    U4 g1, b1, g2, b2, o1, o2;
    g1.u = *(const uint2*)(ar);
    b1.u = *(const uint2*)(ar + 768);
    g2.u = *(const uint2*)(ar + 1536);
    b2.u = *(const uint2*)(ar + 2304);
#pragma unroll
    for (int j = 0; j < 4; ++j) {
      o1.h[j] = __float2bfloat16(sigmoidf_(__bfloat162float(g1.h[j])) * an[j] + __bfloat162float(b1.h[j]));
      o2.h[j] = __float2bfloat16(sigmoidf_(__bfloat162float(g2.h[j])) * an[j] + __bfloat162float(b2.h[j]));
    }
    *(uint2*)(ah_attn + row * CA + 4 * t) = o1.u;
    *(uint2*)(ah_tr + row * CA + 4 * t) = o2.u;
  }
}

// ---------------- f32 -> bf16 cast ----------------
__global__ __launch_bounds__(256) void cvt_bf16(const float* __restrict__ x,
                                                bf16* __restrict__ out, int n8) {
  const int i = blockIdx.x * 256 + threadIdx.x;
  if (i >= n8) return;
  const float4 a = ((const float4*)x)[2 * i], b = ((const float4*)x)[2 * i + 1];
  U8 u;
  u.h[0] = __float2bfloat16(a.x); u.h[1] = __float2bfloat16(a.y);
  u.h[2] = __float2bfloat16(a.z); u.h[3] = __float2bfloat16(a.w);
  u.h[4] = __float2bfloat16(b.x); u.h[5] = __float2bfloat16(b.y);
  u.h[6] = __float2bfloat16(b.z); u.h[7] = __float2bfloat16(b.w);
  *(s8v*)(out + 8 * i) = u.s;
}

// ---------------- transpose+cvt weights: dst[n][k] = src[k][n] * cs[k] ----------------
__global__ __launch_bounds__(256) void transpose_cvt(const float* __restrict__ src,
                                                     bf16* __restrict__ dst, int K, int N,
                                                     const float* __restrict__ colscale,
                                                     size_t srcZ, size_t dstZ, int csZ) {
  __shared__ float tile[32][33];
  const int z = blockIdx.z;
  src += (size_t)z * srcZ;
  dst += (size_t)z * dstZ;
  const int k0 = blockIdx.y * 32, n0 = blockIdx.x * 32;
  const int tx = threadIdx.x & 31, ty = threadIdx.x >> 5;
#pragma unroll
  for (int q = 0; q < 4; ++q) {
    const int k = k0 + ty + 8 * q;
    float v = src[(size_t)k * N + n0 + tx];
    if (colscale) v *= colscale[(size_t)z * csZ + k];
    tile[ty + 8 * q][tx] = v;
  }
  __syncthreads();
#pragma unroll
  for (int q = 0; q < 4; ++q)
    dst[(size_t)(n0 + ty + 8 * q) * K + k0 + tx] = __float2bfloat16(tile[tx][ty + 8 * q]);
}

// ---------------- bf16 transpose (vT) ----------------
__global__ __launch_bounds__(256) void transpose_bf(const bf16* __restrict__ src, int lds_,
                                                    bf16* __restrict__ dst, int ldd) {
  __shared__ bf16 tile[32][33];
  const int n0 = blockIdx.x * 32, r0 = blockIdx.y * 32;
  const int tx = threadIdx.x & 31, ty = threadIdx.x >> 5;
#pragma unroll
  for (int q = 0; q < 4; ++q)
    tile[ty + 8 * q][tx] = src[(size_t)(r0 + ty + 8 * q) * lds_ + n0 + tx];
  __syncthreads();
#pragma unroll
  for (int q = 0; q < 4; ++q)
    dst[(size_t)(n0 + ty + 8 * q) * ldd + r0 + tx] = tile[tx][ty + 8 * q];
}

// ---------------- prep: W2T bf16 [64][128], bias2 f32[64] ----------------
__global__ __launch_bounds__(256) void prep_w2(const float* __restrict__ ln_z_w,
                                               const float* __restrict__ ln_z_b,
                                               const float* __restrict__ wpb,
                                               bf16* __restrict__ W2T,
                                               float* __restrict__ bias2) {
  const int t = threadIdx.x;
  for (int f = t; f < 64 * CZ; f += 256) {
    const int col = f >> 7, c = f & 127, blk = col >> 4, h = col & 15;
    W2T[f] = __float2bfloat16(ln_z_w[blk * CZ + c] * wpb[(blk * CZ + c) * NHEAD + h]);
  }
  if (t < 64) {
    const int blk = t >> 4, h = t & 15;
    float sum = 0.f;
    for (int c = 0; c < CZ; ++c)
      sum += ln_z_b[blk * CZ + c] * wpb[(blk * CZ + c) * NHEAD + h];
    bias2[t] = sum;
  }
}

// ---------------- prep biases ----------------
__global__ __launch_bounds__(256) void prep_biases(const float* __restrict__ bq,
                                                   const float* __restrict__ bsg_attn,
                                                   const float* __restrict__ bsg_tr,
                                                   float* __restrict__ biasQKVG,
                                                   float* __restrict__ biasSG) {
  const int t = blockIdx.x * 256 + threadIdx.x;
  if (t < 4 * 3072) {
    const int b = t / 3072, c = t % 3072;
    biasQKVG[t] = (c < 768) ? bq[b * 768 + c] : 0.f;
  }
  if (t < 6144) {
    const int b = t / 1536, c = t % 1536;
    biasSG[t] = (c < 768) ? bsg_attn[b * 768 + c] : bsg_tr[b * 768 + c - 768];
  }
}

// ---------------- zbias: LN(z)@W2T + bias2 + beta -> bf16 [64][S][S], MFMA ----------------
__global__ __launch_bounds__(256) void zbias_kernel(const float* __restrict__ z,
                                                    const float* __restrict__ beta,
                                                    const bf16* __restrict__ W2T,
                                                    const float* __restrict__ bias2,
                                                    bf16* __restrict__ bias_all) {
  __shared__ s8v zt8[64 * 16];
  __shared__ s8v w2s[64 * 16];
  __shared__ float betas[64][17];
  __shared__ float bias2s[64];
  const int t = threadIdx.x;
  const int i = blockIdx.y, j0 = blockIdx.x * 64;
#pragma unroll
  for (int q = 0; q < 4; ++q) {
    const int u = q * 256 + t;
    const int row = u >> 4, sl = u & 15;
    w2s[row * 16 + (sl ^ (row & 7))] = *(const s8v*)(W2T + row * CZ + sl * 8);
  }
  if (t < 64) bias2s[t] = bias2[t];
  {
    const int j = t >> 2, h4 = t & 3;
    const float4 bv = *(const float4*)(beta + ((size_t)i * S + j0 + j) * NHEAD + 4 * h4);
    betas[j][4 * h4 + 0] = bv.x; betas[j][4 * h4 + 1] = bv.y;
    betas[j][4 * h4 + 2] = bv.z; betas[j][4 * h4 + 3] = bv.w;
  }
  // LN of 64 z rows -> zt8 (swizzled bf16, vector writes)
  {
    const int p = t >> 2, q = t & 3;
    const float* zr = z + ((size_t)i * S + j0 + p) * CZ + q * 32;
    float vals[32];
    float sum = 0.f, sq = 0.f;
#pragma unroll
    for (int k4 = 0; k4 < 8; ++k4) {
      const float4 xv = *(const float4*)(zr + 4 * k4);
      vals[4 * k4 + 0] = xv.x; vals[4 * k4 + 1] = xv.y;
      vals[4 * k4 + 2] = xv.z; vals[4 * k4 + 3] = xv.w;
      sum += xv.x + xv.y + xv.z + xv.w;
      sq += xv.x * xv.x + xv.y * xv.y + xv.z * xv.z + xv.w * xv.w;
    }
    sum += __shfl_xor(sum, 1); sum += __shfl_xor(sum, 2);
    sq += __shfl_xor(sq, 1); sq += __shfl_xor(sq, 2);
    const float m = sum / CZ;
    const float rstd = rsqrtf(sq / CZ - m * m + EPS);
#pragma unroll
    for (int u = 0; u < 4; ++u) {
      U8 pk;
#pragma unroll
      for (int e = 0; e < 8; ++e) pk.h[e] = __float2bfloat16((vals[8 * u + e] - m) * rstd);
      const int cu = 4 * q + u;
      zt8[p * 16 + (cu ^ (p & 7))] = pk.s;
    }
  }
  __syncthreads();
  const int lane = t & 63, wid = t >> 6;
  const int wr = wid >> 1, wc = wid & 1;
  const int ln = lane & 15, lq = lane >> 4;
  f4v acc[2][2] = {};
#pragma unroll
  for (int kk = 0; kk < 4; ++kk) {
    const int sl = (lq + 4 * kk) ^ (ln & 7);
    s8v a[2], b[2];
#pragma unroll
    for (int mi = 0; mi < 2; ++mi) a[mi] = zt8[(32 * wr + 16 * mi + ln) * 16 + sl];
#pragma unroll
    for (int ni = 0; ni < 2; ++ni) b[ni] = w2s[(32 * wc + 16 * ni + ln) * 16 + sl];
#pragma unroll
    for (int mi = 0; mi < 2; ++mi)
#pragma unroll
      for (int ni = 0; ni < 2; ++ni) acc[mi][ni] = mfma16(a[mi], b[ni], acc[mi][ni]);
  }
#pragma unroll
  for (int mi = 0; mi < 2; ++mi)
#pragma unroll
    for (int ni = 0; ni < 2; ++ni) {
      const int col = 32 * wc + 16 * ni + ln;
      const int jb = 32 * wr + 16 * mi + 4 * lq;
      U4 o4;
#pragma unroll
      for (int r = 0; r < 4; ++r)
        o4.h[r] = __float2bfloat16(acc[mi][ni][r] + bias2s[col] + betas[jb + r][col & 15]);
      *(uint2*)(bias_all + (size_t)col * S * S + (size_t)i * S + j0 + jb) = o4.u;
    }
}

// ---------------- MFMA GEMM: C = act(Aeff @ Bt^T + bias) ----------------
// AMODE 0: Aeff=A0 ; 1: sig(A0)*A1 ; 2: silu(A0)*A1
DEV void stC(float* p, float v) { *p = v; }
DEV void stC(bf16* p, float v) { *p = __float2bfloat16(v); }

template <int AMODE>
DEV s8v combineAM(s8v x, s8v y) {
  U8 ux, uy, r;
  ux.s = x; uy.s = y;
#pragma unroll
  for (int j = 0; j < 8; ++j) {
    const float fx = __bfloat162float(ux.h[j]);
    const float fy = __bfloat162float(uy.h[j]);
    const float tt = sigmoidf_(fx);
    r.h[j] = __float2bfloat16((AMODE == 2 ? fx * tt : tt) * fy);
  }
  return r.s;
}

template <int ACT, int AMODE, typename OT>
__global__ __launch_bounds__(256) void gemm_nt(const bf16* __restrict__ A0, int lda0,
                                               const bf16* __restrict__ A1, int lda1,
                                               const bf16* __restrict__ Bt,
                                               const float* __restrict__ bias,
                                               OT* __restrict__ C, int M, int N, int K) {
  __shared__ s8v As[128 * 8];
  __shared__ s8v Bs[128 * 8];
  const int t = threadIdx.x;
  const int lane = t & 63, wid = t >> 6;
  const int wr = wid >> 1, wc = wid & 1;
  const int ln = lane & 15, lq = lane >> 4;
  const int m0 = blockIdx.y * 128, n0 = blockIdx.x * 128;
  int rowS[4], slS[4], swz[4];
#pragma unroll
  for (int q = 0; q < 4; ++q) {
    const int u = q * 256 + t;
    rowS[q] = u >> 3; slS[q] = u & 7;
    swz[q] = rowS[q] * 8 + (slS[q] ^ (rowS[q] & 7));
  }
  f4v acc[4][4] = {};
  s8v ra[4], ra2[4], rb[4];
#pragma unroll
  for (int q = 0; q < 4; ++q) {
    ra[q] = *(const s8v*)(A0 + (size_t)(m0 + rowS[q]) * lda0 + slS[q] * 8);
    if (AMODE != 0) ra2[q] = *(const s8v*)(A1 + (size_t)(m0 + rowS[q]) * lda1 + slS[q] * 8);
    rb[q] = *(const s8v*)(Bt + (size_t)(n0 + rowS[q]) * K + slS[q] * 8);
  }
  for (int ks = 0;;) {
    __syncthreads();
#pragma unroll
    for (int q = 0; q < 4; ++q) {
      As[swz[q]] = (AMODE == 0) ? ra[q] : combineAM<AMODE>(ra[q], ra2[q]);
      Bs[swz[q]] = rb[q];
    }
    const int ksn = ks + 64;
    if (ksn < K) {
#pragma unroll
      for (int q = 0; q < 4; ++q) {
        ra[q] = *(const s8v*)(A0 + (size_t)(m0 + rowS[q]) * lda0 + ksn + slS[q] * 8);
        if (AMODE != 0) ra2[q] = *(const s8v*)(A1 + (size_t)(m0 + rowS[q]) * lda1 + ksn + slS[q] * 8);
        rb[q] = *(const s8v*)(Bt + (size_t)(n0 + rowS[q]) * K + ksn + slS[q] * 8);
      }
    }
    __syncthreads();
#pragma unroll
    for (int kk = 0; kk < 2; ++kk) {
      const int sl = (lq + 4 * kk) ^ (ln & 7);
      s8v a[4], b[4];
#pragma unroll
      for (int mi = 0; mi < 4; ++mi) a[mi] = As[(64 * wr + 16 * mi + ln) * 8 + sl];
#pragma unroll
      for (int ni = 0; ni < 4; ++ni) b[ni] = Bs[(64 * wc + 16 * ni + ln) * 8 + sl];
#pragma unroll
      for (int mi = 0; mi < 4; ++mi)
#pragma unroll
        for (int ni = 0; ni < 4; ++ni) acc[mi][ni] = mfma16(a[mi], b[ni], acc[mi][ni]);
    }
    ks = ksn;
    if (ks >= K) break;
  }
#pragma unroll
  for (int ni = 0; ni < 4; ++ni) {
    const int n = n0 + 64 * wc + 16 * ni + ln;
    const float bv = bias ? bias[n] : 0.f;
#pragma unroll
    for (int mi = 0; mi < 4; ++mi) {
      const int mb = m0 + 64 * wr + 16 * mi + 4 * lq;
#pragma unroll
      for (int r = 0; r < 4; ++r) {
        float v = acc[mi][ni][r] + bv;
        if (ACT == 1) v = sigmoidf_(v);
        stC(&C[(size_t)(mb + r) * N + n], v);
      }
    }
  }
}

// ---------------- flash attention: per (i-tile 64, head) ----------------
__global__ __launch_bounds__(256) void flash_attn(const bf16* __restrict__ qkvg,
                                                  const bf16* __restrict__ vT,
                                                  const bf16* __restrict__ bias_all,
                                                  bf16* __restrict__ ob, int blk) {
  __shared__ s8v Qs[64 * 8];
  __shared__ s8v Ks[2][64 * 8];
  __shared__ s8v Vs[2][48 * 8];
  __shared__ s8v Bs[2][64 * 8];
  __shared__ bf16 PwB[4 * 1024];    // per-wave 16x64, unit-swizzled
  __shared__ float facL[4][16];
  __shared__ float linvL[4][16];
  const int t = threadIdx.x;
  const int lane = t & 63, w = t >> 6;
  const int ln = lane & 15, lq = lane >> 4;
  const int h = blockIdx.y, i0 = blockIdx.x * 64;
  const bf16* bp = bias_all + (size_t)(blk * NHEAD + h) * S * S;
  const float scale = 0.14433756729740643f;  // 1/sqrt(48)

  // stage Q once
#pragma unroll
  for (int uu = 0; uu < 2; ++uu) {
    const int u = t + 256 * uu, row = u >> 3, sl = u & 7;
    s8v qv{};
    if (sl < 6) qv = *(const s8v*)(qkvg + (size_t)(i0 + row) * 3072 + h * DH + sl * 8);
    Qs[row * 8 + (sl ^ (row & 7))] = qv;
  }

  s8v kr[2], br[2], vr0{}, vr1{};
  auto prefetch = [&](int jt) {
    const int j0 = jt * 64;
#pragma unroll
    for (int uu = 0; uu < 2; ++uu) {
      const int u = t + 256 * uu, row = u >> 3, sl = u & 7;
      s8v kv{};
      if (sl < 6) kv = *(const s8v*)(qkvg + (size_t)(j0 + row) * 3072 + 768 + h * DH + sl * 8);
      kr[uu] = kv;
      br[uu] = *(const s8v*)(bp + (size_t)(i0 + row) * S + j0 + sl * 8);
    }
    { const int d = t >> 3, sl = t & 7;
      vr0 = *(const s8v*)(vT + (size_t)(h * DH + d) * S + j0 + sl * 8); }
    if (t < 128) {
      const int u = 256 + t, d = u >> 3, sl = u & 7;
      vr1 = *(const s8v*)(vT + (size_t)(h * DH + d) * S + j0 + sl * 8);
    }
  };
  auto store_tiles = [&](int pb) {
#pragma unroll
    for (int uu = 0; uu < 2; ++uu) {
      const int u = t + 256 * uu, row = u >> 3, sl = u & 7;
      const int ph = row * 8 + (sl ^ (row & 7));
      Ks[pb][ph] = kr[uu];
      Bs[pb][ph] = br[uu];
    }
    { const int d = t >> 3, sl = t & 7;
      Vs[pb][d * 8 + (sl ^ (d & 7))] = vr0; }
    if (t < 128) {
      const int u = 256 + t, d = u >> 3, sl = u & 7;
      Vs[pb][d * 8 + (sl ^ (d & 7))] = vr1;
    }
  };

  float m_run = -3e30f, l_run = 0.f;
  f4v acc_o[3] = {};
  bf16* pw = PwB + w * 1024;

  prefetch(0);
  for (int jt = 0; jt < 16; ++jt) {
    const int pb = jt & 1;
    __syncthreads();
    store_tiles(pb);
    __syncthreads();
    if (jt < 15) prefetch(jt + 1);
    // --- scores: S^T tile, lane: i = ln (wave-rel), j = 16*ja + 4*lq + r ---
    float p[4][4];
    float tmax = -3e30f;
#pragma unroll
    for (int ja = 0; ja < 4; ++ja) {
      f4v accs = {};
#pragma unroll
      for (int ks2 = 0; ks2 < 2; ++ks2) {
        const int sl = (lq + 4 * ks2) ^ (ln & 7);
        const s8v a = Ks[pb][(16 * ja + ln) * 8 + sl];
        const s8v b = Qs[(16 * w + ln) * 8 + sl];
        accs = mfma16(a, b, accs);
      }
      const int jq = 4 * ja + lq;
      const int pu = jq >> 1;
      U4 bv;
      bv.u = *(const uint2*)((const bf16*)(&Bs[pb][0]) +
                             (((16 * w + ln) * 8 + (pu ^ (ln & 7))) * 8 + (jq & 1) * 4));
#pragma unroll
      for (int r = 0; r < 4; ++r) {
        p[ja][r] = accs[r] * scale + __bfloat162float(bv.h[r]);
        tmax = fmaxf(tmax, p[ja][r]);
      }
    }
    tmax = fmaxf(tmax, __shfl_xor(tmax, 16));
    tmax = fmaxf(tmax, __shfl_xor(tmax, 32));
    const float m_new = fmaxf(m_run, tmax);
    const float fac = __expf(m_run - m_new);
    m_run = m_new;
    float psum = 0.f;
#pragma unroll
    for (int ja = 0; ja < 4; ++ja)
#pragma unroll
      for (int r = 0; r < 4; ++r) {
        p[ja][r] = __expf(p[ja][r] - m_new);
        psum += p[ja][r];
      }
    psum += __shfl_xor(psum, 16);
    psum += __shfl_xor(psum, 32);
    l_run = l_run * fac + psum;
    if (lq == 0) facL[w][ln] = fac;
    // write P (bf16) into per-wave swizzled LDS
#pragma unroll
    for (int ja = 0; ja < 4; ++ja) {
      const int ju = 4 * ja + lq;
      const int ph = ju ^ ((ln & 7) << 1);
      U4 pk;
#pragma unroll
      for (int r = 0; r < 4; ++r) pk.h[r] = __float2bfloat16(p[ja][r]);
      *(uint2*)(pw + ln * 64 + ph * 4) = pk.u;
    }
    asm volatile("s_waitcnt lgkmcnt(0)" ::: "memory");
    __builtin_amdgcn_sched_barrier(0);
    // --- PV ---
    const float4 fv = *(const float4*)&facL[w][4 * lq];
#pragma unroll
    for (int ni = 0; ni < 3; ++ni) {
      acc_o[ni][0] *= fv.x; acc_o[ni][1] *= fv.y;
      acc_o[ni][2] *= fv.z; acc_o[ni][3] *= fv.w;
    }
#pragma unroll
    for (int ks2 = 0; ks2 < 2; ++ks2) {
      const int pu0 = (2 * lq + 8 * ks2) ^ ((ln & 7) << 1);
      const s8v pa = *(const s8v*)(pw + ln * 64 + pu0 * 4);
      const int slv = (lq + 4 * ks2) ^ (ln & 7);
#pragma unroll
      for (int ni = 0; ni < 3; ++ni) {
        const s8v vb = Vs[pb][(16 * ni + ln) * 8 + slv];
        acc_o[ni] = mfma16(pa, vb, acc_o[ni]);
      }
    }
  }
  if (lq == 0) linvL[w][ln] = 1.0f / l_run;
  asm volatile("s_waitcnt lgkmcnt(0)" ::: "memory");
  __builtin_amdgcn_sched_barrier(0);
  const float4 lv = *(const float4*)&linvL[w][4 * lq];
  const float lvr[4] = {lv.x, lv.y, lv.z, lv.w};
#pragma unroll
  for (int ni = 0; ni < 3; ++ni)
#pragma unroll
    for (int r = 0; r < 4; ++r) {
      const int m = i0 + 16 * w + 4 * lq + r;
      ob[(size_t)m * CA + h * DH + 16 * ni + ln] = __float2bfloat16(acc_o[ni][r] * lvr[r]);
    }
}

// ---------------- final: out = sgA*att + sgT*tr (f32 out) ----------------
__global__ __launch_bounds__(256) void ew_final(const float* __restrict__ sg, // +b*1536, ld 6144
                                                const bf16* __restrict__ att,
                                                const bf16* __restrict__ tr,
                                                float* __restrict__ out) {
  const int i = blockIdx.x * 256 + threadIdx.x;
  const int row = i / 192, col = (i % 192) * 4;
  const float4 sa = *(const float4*)(sg + (size_t)row * 6144 + col);
  const float4 st = *(const float4*)(sg + (size_t)row * 6144 + 768 + col);
  U4 av, tv;
  av.u = *(const uint2*)(att + (size_t)row * CA + col);
  tv.u = *(const uint2*)(tr + (size_t)row * CA + col);
  float4 o;
  o.x = sa.x * __bfloat162float(av.h[0]) + st.x * __bfloat162float(tv.h[0]);
  o.y = sa.y * __bfloat162float(av.h[1]) + st.y * __bfloat162float(tv.h[1]);
  o.z = sa.z * __bfloat162float(av.h[2]) + st.z * __bfloat162float(tv.h[2]);
  o.w = sa.w * __bfloat162float(av.h[3]) + st.w * __bfloat162float(tv.h[3]);
  *(float4*)(out + (size_t)row * CA + col) = o;
}

__global__ void fill_kernel(float* p, int n, float v) {
  const int i = blockIdx.x * 256 + threadIdx.x;
  if (i < n) p[i] = v;
}

extern "C" void kernel_launch(void* const* d_in, const int* in_sizes, int n_in,
                              void* d_out, int out_size, void* d_ws, size_t ws_size,
                              hipStream_t stream) {
  (void)in_sizes; (void)n_in;
  const float* a_in = (const float*)d_in[0];
  const float* s_in = (const float*)d_in[1];
  const float* z_in = (const float*)d_in[2];
  const float* beta = (const float*)d_in[3];
  const float* ln_s_w_attn = (const float*)d_in[4];
  const float* wg_attn = (const float*)d_in[5];
  const float* wb_attn = (const float*)d_in[6];
  const float* wq = (const float*)d_in[7];
  const float* bq = (const float*)d_in[8];
  const float* wk = (const float*)d_in[9];
  const float* wv = (const float*)d_in[10];
  const float* ln_z_w = (const float*)d_in[11];
  const float* ln_z_b = (const float*)d_in[12];
  const float* wpb = (const float*)d_in[13];
  const float* wgate = (const float*)d_in[14];
  const float* wo = (const float*)d_in[15];
  const float* wsg_attn = (const float*)d_in[16];
  const float* bsg_attn = (const float*)d_in[17];
  const float* ln_s_w_tr = (const float*)d_in[18];
  const float* wg_tr = (const float*)d_in[19];
  const float* wb_tr = (const float*)d_in[20];
  const float* w_swish = (const float*)d_in[21];
  const float* w_gate2 = (const float*)d_in[22];
  const float* wsg_tr = (const float*)d_in[23];
  const float* bsg_tr = (const float*)d_in[24];
  const float* w_out = (const float*)d_in[25];

  char* wp = (char*)d_ws;
  size_t used = 0;
  auto alloc = [&](size_t bytes) -> void* {
    void* p = wp + used;
    used += (bytes + 255) & ~(size_t)255;
    return p;
  };
  bf16* bias_all = (bf16*)alloc((size_t)64 * S * S * 2);
  bf16* WT_ada = (bf16*)alloc((size_t)12288 * 384 * 2);
  bf16* WT_sg = (bf16*)alloc((size_t)6144 * 384 * 2);
  bf16* WT_qkvg = (bf16*)alloc((size_t)4 * 3072 * 768 * 2);
  bf16* WT_wo = (bf16*)alloc((size_t)4 * 768 * 768 * 2);
  bf16* WT_mlp = (bf16*)alloc((size_t)4 * 3072 * 768 * 2);
  bf16* WT_wout = (bf16*)alloc((size_t)4 * 768 * 1536 * 2);
  float* biasQKVG = (float*)alloc(4 * 3072 * 4);
  float* biasSG = (float*)alloc(6144 * 4);
  bf16* W2T = (bf16*)alloc(64 * 128 * 2);
  float* bias2 = (float*)alloc(64 * 4);
  bf16* ada_all = (bf16*)alloc((size_t)S * 12288 * 2);
  float* sg_all = (float*)alloc((size_t)S * 6144 * 4);
  bf16* s_hat = (bf16*)alloc((size_t)S * CS * 2);
  bf16* s_bf = (bf16*)alloc((size_t)S * CS * 2);
  float* a_buf = (float*)alloc((size_t)S * CA * 4);
  bf16* ah_attn = (bf16*)alloc((size_t)S * CA * 2);
  bf16* ah_tr = (bf16*)alloc((size_t)S * CA * 2);
  bf16* qkvg = (bf16*)alloc((size_t)S * 3072 * 2);
  bf16* vT = (bf16*)alloc((size_t)CA * S * 2);
  bf16* ob = (bf16*)alloc((size_t)S * CA * 2);
  bf16* att = (bf16*)alloc((size_t)S * CA * 2);
  bf16* swg = (bf16*)alloc((size_t)S * 3072 * 2);
  bf16* trout = (bf16*)alloc((size_t)S * CA * 2);
  if (used > ws_size) {
    fill_kernel<<<(out_size + 255) / 256, 256, 0, stream>>>((float*)d_out, out_size, 12345.0f);
    return;
  }

  const dim3 B256(256);

  // ---- prep ----
  prep_w2<<<1, B256, 0, stream>>>(ln_z_w, ln_z_b, wpb, W2T, bias2);
  prep_biases<<<48, B256, 0, stream>>>(bq, bsg_attn, bsg_tr, biasQKVG, biasSG);
  transpose_cvt<<<dim3(24, 12, 4), B256, 0, stream>>>(wg_attn, WT_ada + (size_t)0 * 384, 384, 768, ln_s_w_attn, (size_t)CS * CA, (size_t)3072 * 384, CS);
  transpose_cvt<<<dim3(24, 12, 4), B256, 0, stream>>>(wb_attn, WT_ada + (size_t)768 * 384, 384, 768, ln_s_w_attn, (size_t)CS * CA, (size_t)3072 * 384, CS);
  transpose_cvt<<<dim3(24, 12, 4), B256, 0, stream>>>(wg_tr, WT_ada + (size_t)1536 * 384, 384, 768, ln_s_w_tr, (size_t)CS * CA, (size_t)3072 * 384, CS);
  transpose_cvt<<<dim3(24, 12, 4), B256, 0, stream>>>(wb_tr, WT_ada + (size_t)2304 * 384, 384, 768, ln_s_w_tr, (size_t)CS * CA, (size_t)3072 * 384, CS);
  transpose_cvt<<<dim3(24, 12, 4), B256, 0, stream>>>(wsg_attn, WT_sg + (size_t)0 * 384, 384, 768, nullptr, (size_t)CS * CA, (size_t)1536 * 384, 0);
  transpose_cvt<<<dim3(24, 12, 4), B256, 0, stream>>>(wsg_tr, WT_sg + (size_t)768 * 384, 384, 768, nullptr, (size_t)CS * CA, (size_t)1536 * 384, 0);
  transpose_cvt<<<dim3(24, 24, 4), B256, 0, stream>>>(wq, WT_qkvg + (size_t)0 * 768, 768, 768, nullptr, (size_t)CA * CA, (size_t)3072 * 768, 0);
  transpose_cvt<<<dim3(24, 24, 4), B256, 0, stream>>>(wk, WT_qkvg + (size_t)768 * 768, 768, 768, nullptr, (size_t)CA * CA, (size_t)3072 * 768, 0);
  transpose_cvt<<<dim3(24, 24, 4), B256, 0, stream>>>(wv, WT_qkvg + (size_t)1536 * 768, 768, 768, nullptr, (size_t)CA * CA, (size_t)3072 * 768, 0);
  transpose_cvt<<<dim3(24, 24, 4), B256, 0, stream>>>(wgate, WT_qkvg + (size_t)2304 * 768, 768, 768, nullptr, (size_t)CA * CA, (size_t)3072 * 768, 0);
  transpose_cvt<<<dim3(24, 24, 4), B256, 0, stream>>>(wo, WT_wo, 768, 768, nullptr, (size_t)CA * CA, (size_t)768 * 768, 0);
  transpose_cvt<<<dim3(48, 24, 4), B256, 0, stream>>>(w_swish, WT_mlp + (size_t)0 * 768, 768, 1536, nullptr, (size_t)CA * NHID, (size_t)3072 * 768, 0);
  transpose_cvt<<<dim3(48, 24, 4), B256, 0, stream>>>(w_gate2, WT_mlp + (size_t)1536 * 768, 768, 1536, nullptr, (size_t)CA * NHID, (size_t)3072 * 768, 0);
  transpose_cvt<<<dim3(24, 48, 4), B256, 0, stream>>>(w_out, WT_wout, 1536, 768, nullptr, (size_t)NHID * CA, (size_t)768 * 1536, 0);

  rowln_kernel<CS><<<S, B256, 0, stream>>>(s_in, s_hat);
  cvt_bf16<<<(S * CS / 8 + 255) / 256, B256, 0, stream>>>(s_in, s_bf, S * CS / 8);
  zbias_kernel<<<dim3(16, 1024), B256, 0, stream>>>(z_in, beta, W2T, bias2, bias_all);

  gemm_nt<0, 0, bf16><<<dim3(96, 8), B256, 0, stream>>>(s_hat, 384, nullptr, 0, WT_ada, nullptr, ada_all, S, 12288, 384);
  gemm_nt<1, 0, float><<<dim3(48, 8), B256, 0, stream>>>(s_bf, 384, nullptr, 0, WT_sg, biasSG, sg_all, S, 6144, 384);

  const float* a_cur = a_in;
  for (int b = 0; b < NBLK; ++b) {
    ln_adaln2<<<S, B256, 0, stream>>>(a_cur, ada_all + (size_t)b * 3072, ah_attn, ah_tr);
    gemm_nt<0, 0, bf16><<<dim3(24, 8), B256, 0, stream>>>(ah_attn, 768, nullptr, 0, WT_qkvg + (size_t)b * 3072 * 768, biasQKVG + b * 3072, qkvg, S, 3072, 768);
    transpose_bf<<<dim3(24, 32), B256, 0, stream>>>(qkvg + 1536, 3072, vT, S);
    flash_attn<<<dim3(16, 16), B256, 0, stream>>>(qkvg, vT, bias_all, ob, b);
    gemm_nt<0, 1, bf16><<<dim3(6, 8), B256, 0, stream>>>(qkvg + 2304, 3072, ob, 768, WT_wo + (size_t)b * 768 * 768, nullptr, att, S, 768, 768);
    gemm_nt<0, 0, bf16><<<dim3(24, 8), B256, 0, stream>>>(ah_tr, 768, nullptr, 0, WT_mlp + (size_t)b * 3072 * 768, nullptr, swg, S, 3072, 768);
    gemm_nt<0, 2, bf16><<<dim3(6, 8), B256, 0, stream>>>(swg, 3072, swg + 1536, 3072, WT_wout + (size_t)b * 768 * 1536, nullptr, trout, S, 768, 1536);
    float* a_next = (b == NBLK - 1) ? (float*)d_out : a_buf;
    ew_final<<<768, B256, 0, stream>>>(sg_all + (size_t)b * 1536, att, trout, a_next);
    a_cur = a_next;
  }
}

// Round 4
// 666.813 us; speedup vs baseline: 9.1619x; 1.2750x over previous
//
#include <hip/hip_runtime.h>
#include <hip/hip_bf16.h>

typedef __hip_bfloat16 bf16;
typedef __attribute__((ext_vector_type(8))) short s8v;   // 8 bf16 = 16B
typedef __attribute__((ext_vector_type(4))) float f4v;

constexpr int S = 1024, CA = 768, CS = 384, CZ = 128, NHID = 1536;
constexpr int NBLK = 4, NHEAD = 16, DH = 48;
constexpr float EPS = 1e-5f;

#define DEV static __device__ __forceinline__

DEV float sigmoidf_(float x) { return 1.0f / (1.0f + __expf(-x)); }

DEV f4v mfma16(s8v a, s8v b, f4v c) {
  return __builtin_amdgcn_mfma_f32_16x16x32_bf16(a, b, c, 0, 0, 0);
}

union U8 { s8v s; bf16 h[8]; };
union U4 { uint2 u; bf16 h[4]; };

DEV float wred_sum(float v) {
#pragma unroll
  for (int o = 32; o; o >>= 1) v += __shfl_xor(v, o);
  return v;
}

// ---------------- s prep: LN(s)->s_hat, cast->s_bf ----------------
__global__ __launch_bounds__(256) void rowln_s(const float* __restrict__ x,
                                               bf16* __restrict__ s_hat,
                                               bf16* __restrict__ s_bf) {
  constexpr int C = CS, C4 = C / 4;
  __shared__ float red[8];
  const int t = threadIdx.x;
  const size_t row = blockIdx.x;
  float4 v = make_float4(0.f, 0.f, 0.f, 0.f);
  if (t < C4) v = ((const float4*)(x + row * C))[t];
  float sum = v.x + v.y + v.z + v.w;
  float sq = v.x * v.x + v.y * v.y + v.z * v.z + v.w * v.w;
  sum = wred_sum(sum); sq = wred_sum(sq);
  const int wv = t >> 6;
  if ((t & 63) == 0) { red[2 * wv] = sum; red[2 * wv + 1] = sq; }
  __syncthreads();
  sum = red[0] + red[2] + red[4] + red[6];
  sq = red[1] + red[3] + red[5] + red[7];
  const float m = sum / C;
  const float rstd = rsqrtf(sq / C - m * m + EPS);
  if (t < C4) {
    U4 oh, ob_;
    oh.h[0] = __float2bfloat16((v.x - m) * rstd); oh.h[1] = __float2bfloat16((v.y - m) * rstd);
    oh.h[2] = __float2bfloat16((v.z - m) * rstd); oh.h[3] = __float2bfloat16((v.w - m) * rstd);
    ob_.h[0] = __float2bfloat16(v.x); ob_.h[1] = __float2bfloat16(v.y);
    ob_.h[2] = __float2bfloat16(v.z); ob_.h[3] = __float2bfloat16(v.w);
    *(uint2*)(s_hat + row * C + 4 * t) = oh.u;
    *(uint2*)(s_bf + row * C + 4 * t) = ob_.u;
  }
}

// ---------------- fused LN(a) + both adaLNs ----------------
__global__ __launch_bounds__(256) void ln_adaln2(const float* __restrict__ a,
                                                 const bf16* __restrict__ ada,
                                                 bf16* __restrict__ ah_attn,
                                                 bf16* __restrict__ ah_tr) {
  __shared__ float red[8];
  const int t = threadIdx.x;
  const size_t row = blockIdx.x;
  float4 v = make_float4(0.f, 0.f, 0.f, 0.f);
  if (t < 192) v = ((const float4*)(a + row * CA))[t];
  float sum = v.x + v.y + v.z + v.w;
  float sq = v.x * v.x + v.y * v.y + v.z * v.z + v.w * v.w;
  sum = wred_sum(sum); sq = wred_sum(sq);
  const int wv = t >> 6;
  if ((t & 63) == 0) { red[2 * wv] = sum; red[2 * wv + 1] = sq; }
  __syncthreads();
  sum = red[0] + red[2] + red[4] + red[6];
  sq = red[1] + red[3] + red[5] + red[7];
  const float m = sum / CA;
  const float rstd = rsqrtf(sq / CA - m * m + EPS);
  if (t < 192) {
    const float an[4] = {(v.x - m) * rstd, (v.y - m) * rstd, (v.z - m) * rstd, (v.w - m) * rstd};
    const bf16* ar = ada + row * 12288 + 4 * t;
    U4 g1, b1, g2, b2, o1, o2;
    g1.u = *(const uint2*)(ar);
    b1.u = *(const uint2*)(ar + 768);
    g2.u = *(const uint2*)(ar + 1536);
    b2.u = *(const uint2*)(ar + 2304);
#pragma unroll
    for (int j = 0; j < 4; ++j) {
      o1.h[j] = __float2bfloat16(sigmoidf_(__bfloat162float(g1.h[j])) * an[j] + __bfloat162float(b1.h[j]));
      o2.h[j] = __float2bfloat16(sigmoidf_(__bfloat162float(g2.h[j])) * an[j] + __bfloat162float(b2.h[j]));
    }
    *(uint2*)(ah_attn + row * CA + 4 * t) = o1.u;
    *(uint2*)(ah_tr + row * CA + 4 * t) = o2.u;
  }
}

// ---------------- grouped transpose+cvt: dst[n][k] = src[k][n]*cs[k] ----------------
struct TGroup {
  const float* src[6];
  bf16* dst[6];
  const float* cs[6];
  long dstZ[6];
};

__global__ __launch_bounds__(256) void transpose_grp(TGroup g, int K, int N, int csZ) {
  __shared__ float tile[32][33];
  const int z = blockIdx.z, wsel = z >> 2, blk = z & 3;
  const float* src = g.src[wsel] + (size_t)blk * K * N;
  bf16* dst = g.dst[wsel] + (size_t)blk * g.dstZ[wsel];
  const float* cs = g.cs[wsel];
  const int k0 = blockIdx.y * 32, n0 = blockIdx.x * 32;
  const int tx = threadIdx.x & 31, ty = threadIdx.x >> 5;
#pragma unroll
  for (int q = 0; q < 4; ++q) {
    const int k = k0 + ty + 8 * q;
    float v = src[(size_t)k * N + n0 + tx];
    if (cs) v *= cs[(size_t)blk * csZ + k];
    tile[ty + 8 * q][tx] = v;
  }
  __syncthreads();
#pragma unroll
  for (int q = 0; q < 4; ++q)
    dst[(size_t)(n0 + ty + 8 * q) * K + k0 + tx] = __float2bfloat16(tile[tx][ty + 8 * q]);
}

// ---------------- prep: W2T bf16 [64][128], bias2 f32[64] ----------------
__global__ __launch_bounds__(256) void prep_w2(const float* __restrict__ ln_z_w,
                                               const float* __restrict__ ln_z_b,
                                               const float* __restrict__ wpb,
                                               bf16* __restrict__ W2T,
                                               float* __restrict__ bias2) {
  const int t = threadIdx.x;
  for (int f = t; f < 64 * CZ; f += 256) {
    const int col = f >> 7, c = f & 127, blk = col >> 4, h = col & 15;
    W2T[f] = __float2bfloat16(ln_z_w[blk * CZ + c] * wpb[(blk * CZ + c) * NHEAD + h]);
  }
  if (t < 64) {
    const int blk = t >> 4, h = t & 15;
    float sum = 0.f;
    for (int c = 0; c < CZ; ++c)
      sum += ln_z_b[blk * CZ + c] * wpb[(blk * CZ + c) * NHEAD + h];
    bias2[t] = sum;
  }
}

__global__ __launch_bounds__(256) void prep_biases(const float* __restrict__ bq,
                                                   const float* __restrict__ bsg_attn,
                                                   const float* __restrict__ bsg_tr,
                                                   float* __restrict__ biasQKVG,
                                                   float* __restrict__ biasSG) {
  const int t = blockIdx.x * 256 + threadIdx.x;
  if (t < 4 * 3072) {
    const int b = t / 3072, c = t % 3072;
    biasQKVG[t] = (c < 768) ? bq[b * 768 + c] : 0.f;
  }
  if (t < 6144) {
    const int b = t / 1536, c = t % 1536;
    biasSG[t] = (c < 768) ? bsg_attn[b * 768 + c] : bsg_tr[b * 768 + c - 768];
  }
}

// ---------------- zbias: LN(z)@W2T + bias2 + beta -> bf16 [64][S][S], MFMA ----------------
__global__ __launch_bounds__(256) void zbias_kernel(const float* __restrict__ z,
                                                    const float* __restrict__ beta,
                                                    const bf16* __restrict__ W2T,
                                                    const float* __restrict__ bias2,
                                                    bf16* __restrict__ bias_all) {
  __shared__ s8v zt8[64 * 16];
  __shared__ s8v w2s[64 * 16];
  __shared__ float betas[64][17];
  __shared__ float bias2s[64];
  __shared__ bf16 obuf[64][72];
  const int t = threadIdx.x;
  const int i = blockIdx.y, j0 = blockIdx.x * 64;
#pragma unroll
  for (int q = 0; q < 4; ++q) {
    const int u = q * 256 + t;
    const int row = u >> 4, sl = u & 15;
    w2s[row * 16 + (sl ^ (row & 7))] = *(const s8v*)(W2T + row * CZ + sl * 8);
  }
  if (t < 64) bias2s[t] = bias2[t];
  {
    const int j = t >> 2, h4 = t & 3;
    const float4 bv = *(const float4*)(beta + ((size_t)i * S + j0 + j) * NHEAD + 4 * h4);
    betas[j][4 * h4 + 0] = bv.x; betas[j][4 * h4 + 1] = bv.y;
    betas[j][4 * h4 + 2] = bv.z; betas[j][4 * h4 + 3] = bv.w;
  }
  {
    const int p = t >> 2, q = t & 3;
    const float* zr = z + ((size_t)i * S + j0 + p) * CZ + q * 32;
    float vals[32];
    float sum = 0.f, sq = 0.f;
#pragma unroll
    for (int k4 = 0; k4 < 8; ++k4) {
      const float4 xv = *(const float4*)(zr + 4 * k4);
      vals[4 * k4 + 0] = xv.x; vals[4 * k4 + 1] = xv.y;
      vals[4 * k4 + 2] = xv.z; vals[4 * k4 + 3] = xv.w;
      sum += xv.x + xv.y + xv.z + xv.w;
      sq += xv.x * xv.x + xv.y * xv.y + xv.z * xv.z + xv.w * xv.w;
    }
    sum += __shfl_xor(sum, 1); sum += __shfl_xor(sum, 2);
    sq += __shfl_xor(sq, 1); sq += __shfl_xor(sq, 2);
    const float m = sum / CZ;
    const float rstd = rsqrtf(sq / CZ - m * m + EPS);
#pragma unroll
    for (int u = 0; u < 4; ++u) {
      U8 pk;
#pragma unroll
      for (int e = 0; e < 8; ++e) pk.h[e] = __float2bfloat16((vals[8 * u + e] - m) * rstd);
      const int cu = 4 * q + u;
      zt8[p * 16 + (cu ^ (p & 7))] = pk.s;
    }
  }
  __syncthreads();
  const int lane = t & 63, wid = t >> 6;
  const int wr = wid >> 1, wc = wid & 1;
  const int ln = lane & 15, lq = lane >> 4;
  f4v acc[2][2] = {};
#pragma unroll
  for (int kk = 0; kk < 4; ++kk) {
    const int sl = (lq + 4 * kk) ^ (ln & 7);
    s8v a[2], b[2];
#pragma unroll
    for (int mi = 0; mi < 2; ++mi) a[mi] = zt8[(32 * wr + 16 * mi + ln) * 16 + sl];
#pragma unroll
    for (int ni = 0; ni < 2; ++ni) b[ni] = w2s[(32 * wc + 16 * ni + ln) * 16 + sl];
#pragma unroll
    for (int mi = 0; mi < 2; ++mi)
#pragma unroll
      for (int ni = 0; ni < 2; ++ni) acc[mi][ni] = mfma16(a[mi], b[ni], acc[mi][ni]);
  }
  // stage into LDS (col-major rows) for coalesced global writes
#pragma unroll
  for (int mi = 0; mi < 2; ++mi)
#pragma unroll
    for (int ni = 0; ni < 2; ++ni) {
      const int col = 32 * wc + 16 * ni + ln;
      const int jb = 32 * wr + 16 * mi + 4 * lq;
      U4 o4;
#pragma unroll
      for (int r = 0; r < 4; ++r)
        o4.h[r] = __float2bfloat16(acc[mi][ni][r] + bias2s[col] + betas[jb + r][col & 15]);
      *(uint2*)&obuf[col][jb] = o4.u;
    }
  __syncthreads();
  {
    const int oc = t >> 2, js = (t & 3) * 16;
    bf16* dp = bias_all + (size_t)oc * S * S + (size_t)i * S + j0 + js;
    *(s8v*)dp = *(const s8v*)&obuf[oc][js];
    *(s8v*)(dp + 8) = *(const s8v*)&obuf[oc][js + 8];
  }
}

// ---------------- MFMA GEMM (templated, for hoisted GEMMs) ----------------
DEV void stC(float* p, float v) { *p = v; }
DEV void stC(bf16* p, float v) { *p = __float2bfloat16(v); }

template <int ACT, typename OT>
__global__ __launch_bounds__(256) void gemm_nt(const bf16* __restrict__ A0, int lda0,
                                               const bf16* __restrict__ Bt,
                                               const float* __restrict__ bias,
                                               OT* __restrict__ C, int M, int N, int K) {
  __shared__ s8v As[128 * 8];
  __shared__ s8v Bs[128 * 8];
  const int t = threadIdx.x;
  const int lane = t & 63, wid = t >> 6;
  const int wr = wid >> 1, wc = wid & 1;
  const int ln = lane & 15, lq = lane >> 4;
  const int m0 = blockIdx.y * 128, n0 = blockIdx.x * 128;
  int rowS[4], slS[4], swz[4];
#pragma unroll
  for (int q = 0; q < 4; ++q) {
    const int u = q * 256 + t;
    rowS[q] = u >> 3; slS[q] = u & 7;
    swz[q] = rowS[q] * 8 + (slS[q] ^ (rowS[q] & 7));
  }
  f4v acc[4][4] = {};
  s8v ra[4], rb[4];
#pragma unroll
  for (int q = 0; q < 4; ++q) {
    ra[q] = *(const s8v*)(A0 + (size_t)(m0 + rowS[q]) * lda0 + slS[q] * 8);
    rb[q] = *(const s8v*)(Bt + (size_t)(n0 + rowS[q]) * K + slS[q] * 8);
  }
  for (int ks = 0;;) {
    __syncthreads();
#pragma unroll
    for (int q = 0; q < 4; ++q) { As[swz[q]] = ra[q]; Bs[swz[q]] = rb[q]; }
    const int ksn = ks + 64;
    if (ksn < K) {
#pragma unroll
      for (int q = 0; q < 4; ++q) {
        ra[q] = *(const s8v*)(A0 + (size_t)(m0 + rowS[q]) * lda0 + ksn + slS[q] * 8);
        rb[q] = *(const s8v*)(Bt + (size_t)(n0 + rowS[q]) * K + ksn + slS[q] * 8);
      }
    }
    __syncthreads();
#pragma unroll
    for (int kk = 0; kk < 2; ++kk) {
      const int sl = (lq + 4 * kk) ^ (ln & 7);
      s8v a[4], b[4];
#pragma unroll
      for (int mi = 0; mi < 4; ++mi) a[mi] = As[(64 * wr + 16 * mi + ln) * 8 + sl];
#pragma unroll
      for (int ni = 0; ni < 4; ++ni) b[ni] = Bs[(64 * wc + 16 * ni + ln) * 8 + sl];
#pragma unroll
      for (int mi = 0; mi < 4; ++mi)
#pragma unroll
        for (int ni = 0; ni < 4; ++ni) acc[mi][ni] = mfma16(a[mi], b[ni], acc[mi][ni]);
    }
    ks = ksn;
    if (ks >= K) break;
  }
#pragma unroll
  for (int ni = 0; ni < 4; ++ni) {
    const int n = n0 + 64 * wc + 16 * ni + ln;
    const float bv = bias ? bias[n] : 0.f;
#pragma unroll
    for (int mi = 0; mi < 4; ++mi) {
      const int mb = m0 + 64 * wr + 16 * mi + 4 * lq;
#pragma unroll
      for (int r = 0; r < 4; ++r) {
        float v = acc[mi][ni][r] + bv;
        if (ACT == 1) v = sigmoidf_(v);
        stC(&C[(size_t)(mb + r) * N + n], v);
      }
    }
  }
}

// ---------------- paired MFMA GEMM: two problems, blockIdx.z selects ----------------
// amode 0: Aeff=A0 ; 1: sig(A0)*A1 ; 2: silu(A0)*A1. Optional fused vT transpose.
struct GemmPairArgs {
  const bf16* A0[2]; int lda0[2];
  const bf16* A1[2]; int lda1[2];
  const bf16* Bt[2];
  const float* bias[2];
  bf16* C[2];
  int K[2]; int amode[2];
  bf16* vT;   // if set: z==0 cols [1536,2304) diverted to vT[n-1536][m], C skipped
};

DEV s8v combineRT(s8v x, s8v y, int amode) {
  U8 ux, uy, r;
  ux.s = x; uy.s = y;
#pragma unroll
  for (int j = 0; j < 8; ++j) {
    const float fx = __bfloat162float(ux.h[j]);
    const float fy = __bfloat162float(uy.h[j]);
    const float tt = sigmoidf_(fx);
    r.h[j] = __float2bfloat16((amode == 2 ? fx * tt : tt) * fy);
  }
  return r.s;
}

__global__ __launch_bounds__(256) void gemm_pair(GemmPairArgs ga, int N) {
  __shared__ s8v As[128 * 8];
  __shared__ s8v Bs[128 * 8];
  const int z = blockIdx.z;
  const bf16* A0 = ga.A0[z]; const int lda0 = ga.lda0[z];
  const bf16* A1 = ga.A1[z]; const int lda1 = ga.lda1[z];
  const bf16* Bt = ga.Bt[z];
  const float* bias = ga.bias[z];
  bf16* C = ga.C[z];
  const int K = ga.K[z], amode = ga.amode[z];
  const int t = threadIdx.x;
  const int lane = t & 63, wid = t >> 6;
  const int wr = wid >> 1, wc = wid & 1;
  const int ln = lane & 15, lq = lane >> 4;
  const int m0 = blockIdx.y * 128, n0 = blockIdx.x * 128;
  int rowS[4], slS[4], swz[4];
#pragma unroll
  for (int q = 0; q < 4; ++q) {
    const int u = q * 256 + t;
    rowS[q] = u >> 3; slS[q] = u & 7;
    swz[q] = rowS[q] * 8 + (slS[q] ^ (rowS[q] & 7));
  }
  f4v acc[4][4] = {};
  s8v ra[4], ra2[4], rb[4];
#pragma unroll
  for (int q = 0; q < 4; ++q) {
    ra[q] = *(const s8v*)(A0 + (size_t)(m0 + rowS[q]) * lda0 + slS[q] * 8);
    if (amode != 0) ra2[q] = *(const s8v*)(A1 + (size_t)(m0 + rowS[q]) * lda1 + slS[q] * 8);
    rb[q] = *(const s8v*)(Bt + (size_t)(n0 + rowS[q]) * K + slS[q] * 8);
  }
  for (int ks = 0;;) {
    __syncthreads();
#pragma unroll
    for (int q = 0; q < 4; ++q) {
      As[swz[q]] = (amode == 0) ? ra[q] : combineRT(ra[q], ra2[q], amode);
      Bs[swz[q]] = rb[q];
    }
    const int ksn = ks + 64;
    if (ksn < K) {
#pragma unroll
      for (int q = 0; q < 4; ++q) {
        ra[q] = *(const s8v*)(A0 + (size_t)(m0 + rowS[q]) * lda0 + ksn + slS[q] * 8);
        if (amode != 0) ra2[q] = *(const s8v*)(A1 + (size_t)(m0 + rowS[q]) * lda1 + ksn + slS[q] * 8);
        rb[q] = *(const s8v*)(Bt + (size_t)(n0 + rowS[q]) * K + ksn + slS[q] * 8);
      }
    }
    __syncthreads();
#pragma unroll
    for (int kk = 0; kk < 2; ++kk) {
      const int sl = (lq + 4 * kk) ^ (ln & 7);
      s8v a[4], b[4];
#pragma unroll
      for (int mi = 0; mi < 4; ++mi) a[mi] = As[(64 * wr + 16 * mi + ln) * 8 + sl];
#pragma unroll
      for (int ni = 0; ni < 4; ++ni) b[ni] = Bs[(64 * wc + 16 * ni + ln) * 8 + sl];
#pragma unroll
      for (int mi = 0; mi < 4; ++mi)
#pragma unroll
        for (int ni = 0; ni < 4; ++ni) acc[mi][ni] = mfma16(a[mi], b[ni], acc[mi][ni]);
    }
    ks = ksn;
    if (ks >= K) break;
  }
  const bool vdiv = (ga.vT != nullptr) && (z == 0) && (n0 >= 1536) && (n0 < 2304);
#pragma unroll
  for (int ni = 0; ni < 4; ++ni) {
    const int n = n0 + 64 * wc + 16 * ni + ln;
    const float bv = bias ? bias[n] : 0.f;
#pragma unroll
    for (int mi = 0; mi < 4; ++mi) {
      const int mb = m0 + 64 * wr + 16 * mi + 4 * lq;
      if (vdiv) {
        U4 o4;
#pragma unroll
        for (int r = 0; r < 4; ++r) o4.h[r] = __float2bfloat16(acc[mi][ni][r] + bv);
        *(uint2*)(ga.vT + (size_t)(n - 1536) * S + mb) = o4.u;
      } else {
#pragma unroll
        for (int r = 0; r < 4; ++r)
          C[(size_t)(mb + r) * N + n] = __float2bfloat16(acc[mi][ni][r] + bv);
      }
    }
  }
}

// ---------------- flash attention: per (i-tile 64, head) ----------------
__global__ __launch_bounds__(256) void flash_attn(const bf16* __restrict__ qkvg,
                                                  const bf16* __restrict__ vT,
                                                  const bf16* __restrict__ bias_all,
                                                  bf16* __restrict__ ob, int blk) {
  __shared__ s8v Qs[64 * 8];
  __shared__ s8v Ks[2][64 * 8];
  __shared__ s8v Vs[2][48 * 8];
  __shared__ s8v Bs[2][64 * 8];
  __shared__ bf16 PwB[4 * 1024];
  __shared__ float facL[4][16];
  __shared__ float linvL[4][16];
  const int t = threadIdx.x;
  const int lane = t & 63, w = t >> 6;
  const int ln = lane & 15, lq = lane >> 4;
  const int h = blockIdx.y, i0 = blockIdx.x * 64;
  const bf16* bp = bias_all + (size_t)(blk * NHEAD + h) * S * S;
  const float scale = 0.14433756729740643f;

#pragma unroll
  for (int uu = 0; uu < 2; ++uu) {
    const int u = t + 256 * uu, row = u >> 3, sl = u & 7;
    s8v qv{};
    if (sl < 6) qv = *(const s8v*)(qkvg + (size_t)(i0 + row) * 3072 + h * DH + sl * 8);
    Qs[row * 8 + (sl ^ (row & 7))] = qv;
  }

  s8v kr[2], br[2], vr0{}, vr1{};
  auto prefetch = [&](int jt) {
    const int j0 = jt * 64;
#pragma unroll
    for (int uu = 0; uu < 2; ++uu) {
      const int u = t + 256 * uu, row = u >> 3, sl = u & 7;
      s8v kv{};
      if (sl < 6) kv = *(const s8v*)(qkvg + (size_t)(j0 + row) * 3072 + 768 + h * DH + sl * 8);
      kr[uu] = kv;
      br[uu] = *(const s8v*)(bp + (size_t)(i0 + row) * S + j0 + sl * 8);
    }
    { const int d = t >> 3, sl = t & 7;
      vr0 = *(const s8v*)(vT + (size_t)(h * DH + d) * S + j0 + sl * 8); }
    if (t < 128) {
      const int u = 256 + t, d = u >> 3, sl = u & 7;
      vr1 = *(const s8v*)(vT + (size_t)(h * DH + d) * S + j0 + sl * 8);
    }
  };
  auto store_tiles = [&](int pb) {
#pragma unroll
    for (int uu = 0; uu < 2; ++uu) {
      const int u = t + 256 * uu, row = u >> 3, sl = u & 7;
      const int ph = row * 8 + (sl ^ (row & 7));
      Ks[pb][ph] = kr[uu];
      Bs[pb][ph] = br[uu];
    }
    { const int d = t >> 3, sl = t & 7;
      Vs[pb][d * 8 + (sl ^ (d & 7))] = vr0; }
    if (t < 128) {
      const int u = 256 + t, d = u >> 3, sl = u & 7;
      Vs[pb][d * 8 + (sl ^ (d & 7))] = vr1;
    }
  };

  float m_run = -3e30f, l_run = 0.f;
  f4v acc_o[3] = {};
  bf16* pw = PwB + w * 1024;

  prefetch(0);
  for (int jt = 0; jt < 16; ++jt) {
    const int pb = jt & 1;
    __syncthreads();
    store_tiles(pb);
    __syncthreads();
    if (jt < 15) prefetch(jt + 1);
    float p[4][4];
    float tmax = -3e30f;
#pragma unroll
    for (int ja = 0; ja < 4; ++ja) {
      f4v accs = {};
#pragma unroll
      for (int ks2 = 0; ks2 < 2; ++ks2) {
        const int sl = (lq + 4 * ks2) ^ (ln & 7);
        const s8v a = Ks[pb][(16 * ja + ln) * 8 + sl];
        const s8v b = Qs[(16 * w + ln) * 8 + sl];
        accs = mfma16(a, b, accs);
      }
      const int jq = 4 * ja + lq;
      const int pu = jq >> 1;
      U4 bv;
      bv.u = *(const uint2*)((const bf16*)(&Bs[pb][0]) +
                             (((16 * w + ln) * 8 + (pu ^ (ln & 7))) * 8 + (jq & 1) * 4));
#pragma unroll
      for (int r = 0; r < 4; ++r) {
        p[ja][r] = accs[r] * scale + __bfloat162float(bv.h[r]);
        tmax = fmaxf(tmax, p[ja][r]);
      }
    }
    tmax = fmaxf(tmax, __shfl_xor(tmax, 16));
    tmax = fmaxf(tmax, __shfl_xor(tmax, 32));
    const float m_new = fmaxf(m_run, tmax);
    const float fac = __expf(m_run - m_new);
    m_run = m_new;
    float psum = 0.f;
#pragma unroll
    for (int ja = 0; ja < 4; ++ja)
#pragma unroll
      for (int r = 0; r < 4; ++r) {
        p[ja][r] = __expf(p[ja][r] - m_new);
        psum += p[ja][r];
      }
    psum += __shfl_xor(psum, 16);
    psum += __shfl_xor(psum, 32);
    l_run = l_run * fac + psum;
    if (lq == 0) facL[w][ln] = fac;
#pragma unroll
    for (int ja = 0; ja < 4; ++ja) {
      const int ju = 4 * ja + lq;
      const int ph = ju ^ ((ln & 7) << 1);
      U4 pk;
#pragma unroll
      for (int r = 0; r < 4; ++r) pk.h[r] = __float2bfloat16(p[ja][r]);
      *(uint2*)(pw + ln * 64 + ph * 4) = pk.u;
    }
    asm volatile("s_waitcnt lgkmcnt(0)" ::: "memory");
    __builtin_amdgcn_sched_barrier(0);
    const float4 fv = *(const float4*)&facL[w][4 * lq];
#pragma unroll
    for (int ni = 0; ni < 3; ++ni) {
      acc_o[ni][0] *= fv.x; acc_o[ni][1] *= fv.y;
      acc_o[ni][2] *= fv.z; acc_o[ni][3] *= fv.w;
    }
#pragma unroll
    for (int ks2 = 0; ks2 < 2; ++ks2) {
      const int pu0 = (2 * lq + 8 * ks2) ^ ((ln & 7) << 1);
      const s8v pa = *(const s8v*)(pw + ln * 64 + pu0 * 4);
      const int slv = (lq + 4 * ks2) ^ (ln & 7);
#pragma unroll
      for (int ni = 0; ni < 3; ++ni) {
        const s8v vb = Vs[pb][(16 * ni + ln) * 8 + slv];
        acc_o[ni] = mfma16(pa, vb, acc_o[ni]);
      }
    }
  }
  if (lq == 0) linvL[w][ln] = 1.0f / l_run;
  asm volatile("s_waitcnt lgkmcnt(0)" ::: "memory");
  __builtin_amdgcn_sched_barrier(0);
  const float4 lv = *(const float4*)&linvL[w][4 * lq];
  const float lvr[4] = {lv.x, lv.y, lv.z, lv.w};
#pragma unroll
  for (int ni = 0; ni < 3; ++ni)
#pragma unroll
    for (int r = 0; r < 4; ++r) {
      const int m = i0 + 16 * w + 4 * lq + r;
      ob[(size_t)m * CA + h * DH + 16 * ni + ln] = __float2bfloat16(acc_o[ni][r] * lvr[r]);
    }
}

// ---------------- final: out = sgA*att + sgT*tr (f32 out) ----------------
__global__ __launch_bounds__(256) void ew_final(const float* __restrict__ sg,
                                                const bf16* __restrict__ att,
                                                const bf16* __restrict__ tr,
                                                float* __restrict__ out) {
  const int i = blockIdx.x * 256 + threadIdx.x;
  const int row = i / 192, col = (i % 192) * 4;
  const float4 sa = *(const float4*)(sg + (size_t)row * 6144 + col);
  const float4 st = *(const float4*)(sg + (size_t)row * 6144 + 768 + col);
  U4 av, tv;
  av.u = *(const uint2*)(att + (size_t)row * CA + col);
  tv.u = *(const uint2*)(tr + (size_t)row * CA + col);
  float4 o;
  o.x = sa.x * __bfloat162float(av.h[0]) + st.x * __bfloat162float(tv.h[0]);
  o.y = sa.y * __bfloat162float(av.h[1]) + st.y * __bfloat162float(tv.h[1]);
  o.z = sa.z * __bfloat162float(av.h[2]) + st.z * __bfloat162float(tv.h[2]);
  o.w = sa.w * __bfloat162float(av.h[3]) + st.w * __bfloat162float(tv.h[3]);
  *(float4*)(out + (size_t)row * CA + col) = o;
}

__global__ void fill_kernel(float* p, int n, float v) {
  const int i = blockIdx.x * 256 + threadIdx.x;
  if (i < n) p[i] = v;
}

extern "C" void kernel_launch(void* const* d_in, const int* in_sizes, int n_in,
                              void* d_out, int out_size, void* d_ws, size_t ws_size,
                              hipStream_t stream) {
  (void)in_sizes; (void)n_in;
  const float* a_in = (const float*)d_in[0];
  const float* s_in = (const float*)d_in[1];
  const float* z_in = (const float*)d_in[2];
  const float* beta = (const float*)d_in[3];
  const float* ln_s_w_attn = (const float*)d_in[4];
  const float* wg_attn = (const float*)d_in[5];
  const float* wb_attn = (const float*)d_in[6];
  const float* wq = (const float*)d_in[7];
  const float* bq = (const float*)d_in[8];
  const float* wk = (const float*)d_in[9];
  const float* wv = (const float*)d_in[10];
  const float* ln_z_w = (const float*)d_in[11];
  const float* ln_z_b = (const float*)d_in[12];
  const float* wpb = (const float*)d_in[13];
  const float* wgate = (const float*)d_in[14];
  const float* wo = (const float*)d_in[15];
  const float* wsg_attn = (const float*)d_in[16];
  const float* bsg_attn = (const float*)d_in[17];
  const float* ln_s_w_tr = (const float*)d_in[18];
  const float* wg_tr = (const float*)d_in[19];
  const float* wb_tr = (const float*)d_in[20];
  const float* w_swish = (const float*)d_in[21];
  const float* w_gate2 = (const float*)d_in[22];
  const float* wsg_tr = (const float*)d_in[23];
  const float* bsg_tr = (const float*)d_in[24];
  const float* w_out = (const float*)d_in[25];

  char* wp = (char*)d_ws;
  size_t used = 0;
  auto alloc = [&](size_t bytes) -> void* {
    void* p = wp + used;
    used += (bytes + 255) & ~(size_t)255;
    return p;
  };
  bf16* bias_all = (bf16*)alloc((size_t)64 * S * S * 2);
  bf16* WT_ada = (bf16*)alloc((size_t)4 * 3072 * 384 * 2);
  bf16* WT_sg = (bf16*)alloc((size_t)4 * 1536 * 384 * 2);
  bf16* WT_qkvg = (bf16*)alloc((size_t)4 * 3072 * 768 * 2);
  bf16* WT_wo = (bf16*)alloc((size_t)4 * 768 * 768 * 2);
  bf16* WT_mlp = (bf16*)alloc((size_t)4 * 3072 * 768 * 2);
  bf16* WT_wout = (bf16*)alloc((size_t)4 * 768 * 1536 * 2);
  float* biasQKVG = (float*)alloc(4 * 3072 * 4);
  float* biasSG = (float*)alloc(6144 * 4);
  bf16* W2T = (bf16*)alloc(64 * 128 * 2);
  float* bias2 = (float*)alloc(64 * 4);
  bf16* ada_all = (bf16*)alloc((size_t)S * 12288 * 2);
  float* sg_all = (float*)alloc((size_t)S * 6144 * 4);
  bf16* s_hat = (bf16*)alloc((size_t)S * CS * 2);
  bf16* s_bf = (bf16*)alloc((size_t)S * CS * 2);
  float* a_buf = (float*)alloc((size_t)S * CA * 4);
  bf16* ah_attn = (bf16*)alloc((size_t)S * CA * 2);
  bf16* ah_tr = (bf16*)alloc((size_t)S * CA * 2);
  bf16* qkvg = (bf16*)alloc((size_t)S * 3072 * 2);
  bf16* vT = (bf16*)alloc((size_t)CA * S * 2);
  bf16* ob = (bf16*)alloc((size_t)S * CA * 2);
  bf16* att = (bf16*)alloc((size_t)S * CA * 2);
  bf16* swg = (bf16*)alloc((size_t)S * 3072 * 2);
  bf16* trout = (bf16*)alloc((size_t)S * CA * 2);
  if (used > ws_size) {
    fill_kernel<<<(out_size + 255) / 256, 256, 0, stream>>>((float*)d_out, out_size, 12345.0f);
    return;
  }

  const dim3 B256(256);

  prep_w2<<<1, B256, 0, stream>>>(ln_z_w, ln_z_b, wpb, W2T, bias2);
  prep_biases<<<48, B256, 0, stream>>>(bq, bsg_attn, bsg_tr, biasQKVG, biasSG);

  {  // group 1: K=384, N=768 (ada x4 + sg x2)
    TGroup g{};
    g.src[0] = wg_attn;  g.dst[0] = WT_ada + (size_t)0 * 384;    g.cs[0] = ln_s_w_attn; g.dstZ[0] = 3072 * 384;
    g.src[1] = wb_attn;  g.dst[1] = WT_ada + (size_t)768 * 384;  g.cs[1] = ln_s_w_attn; g.dstZ[1] = 3072 * 384;
    g.src[2] = wg_tr;    g.dst[2] = WT_ada + (size_t)1536 * 384; g.cs[2] = ln_s_w_tr;   g.dstZ[2] = 3072 * 384;
    g.src[3] = wb_tr;    g.dst[3] = WT_ada + (size_t)2304 * 384; g.cs[3] = ln_s_w_tr;   g.dstZ[3] = 3072 * 384;
    g.src[4] = wsg_attn; g.dst[4] = WT_sg + (size_t)0 * 384;     g.cs[4] = nullptr;     g.dstZ[4] = 1536 * 384;
    g.src[5] = wsg_tr;   g.dst[5] = WT_sg + (size_t)768 * 384;   g.cs[5] = nullptr;     g.dstZ[5] = 1536 * 384;
    transpose_grp<<<dim3(24, 12, 24), B256, 0, stream>>>(g, 384, 768, CS);
  }
  {  // group 2: K=768, N=768 (wq,wk,wv,wgate,wo)
    TGroup g{};
    g.src[0] = wq;    g.dst[0] = WT_qkvg + (size_t)0 * 768;    g.dstZ[0] = 3072 * 768;
    g.src[1] = wk;    g.dst[1] = WT_qkvg + (size_t)768 * 768;  g.dstZ[1] = 3072 * 768;
    g.src[2] = wv;    g.dst[2] = WT_qkvg + (size_t)1536 * 768; g.dstZ[2] = 3072 * 768;
    g.src[3] = wgate; g.dst[3] = WT_qkvg + (size_t)2304 * 768; g.dstZ[3] = 3072 * 768;
    g.src[4] = wo;    g.dst[4] = WT_wo;                        g.dstZ[4] = 768 * 768;
    transpose_grp<<<dim3(24, 24, 20), B256, 0, stream>>>(g, 768, 768, 0);
  }
  {  // group 3: K=768, N=1536 (w_swish, w_gate2)
    TGroup g{};
    g.src[0] = w_swish; g.dst[0] = WT_mlp + (size_t)0 * 768;    g.dstZ[0] = 3072 * 768;
    g.src[1] = w_gate2; g.dst[1] = WT_mlp + (size_t)1536 * 768; g.dstZ[1] = 3072 * 768;
    transpose_grp<<<dim3(48, 24, 8), B256, 0, stream>>>(g, 768, 1536, 0);
  }
  {  // group 4: K=1536, N=768 (w_out)
    TGroup g{};
    g.src[0] = w_out; g.dst[0] = WT_wout; g.dstZ[0] = 768 * 1536;
    transpose_grp<<<dim3(24, 48, 4), B256, 0, stream>>>(g, 1536, 768, 0);
  }

  rowln_s<<<S, B256, 0, stream>>>(s_in, s_hat, s_bf);
  zbias_kernel<<<dim3(16, 1024), B256, 0, stream>>>(z_in, beta, W2T, bias2, bias_all);

  gemm_nt<0, bf16><<<dim3(96, 8), B256, 0, stream>>>(s_hat, 384, WT_ada, nullptr, ada_all, S, 12288, 384);
  gemm_nt<1, float><<<dim3(48, 8), B256, 0, stream>>>(s_bf, 384, WT_sg, biasSG, sg_all, S, 6144, 384);

  const float* a_cur = a_in;
  for (int b = 0; b < NBLK; ++b) {
    ln_adaln2<<<S, B256, 0, stream>>>(a_cur, ada_all + (size_t)b * 3072, ah_attn, ah_tr);
    {  // merged: z=0 qkvg (with fused vT), z=1 mlp(swg)
      GemmPairArgs ga{};
      ga.A0[0] = ah_attn; ga.lda0[0] = 768; ga.A1[0] = nullptr; ga.lda1[0] = 0;
      ga.Bt[0] = WT_qkvg + (size_t)b * 3072 * 768; ga.bias[0] = biasQKVG + b * 3072;
      ga.C[0] = qkvg; ga.K[0] = 768; ga.amode[0] = 0;
      ga.A0[1] = ah_tr; ga.lda0[1] = 768; ga.A1[1] = nullptr; ga.lda1[1] = 0;
      ga.Bt[1] = WT_mlp + (size_t)b * 3072 * 768; ga.bias[1] = nullptr;
      ga.C[1] = swg; ga.K[1] = 768; ga.amode[1] = 0;
      ga.vT = vT;
      gemm_pair<<<dim3(24, 8, 2), B256, 0, stream>>>(ga, 3072);
    }
    flash_attn<<<dim3(16, 16), B256, 0, stream>>>(qkvg, vT, bias_all, ob, b);
    {  // merged: z=0 att = (sig(gate)*ob)@wo ; z=1 trout = swiglu(swg)@w_out
      GemmPairArgs ga{};
      ga.A0[0] = qkvg + 2304; ga.lda0[0] = 3072; ga.A1[0] = ob; ga.lda1[0] = 768;
      ga.Bt[0] = WT_wo + (size_t)b * 768 * 768; ga.bias[0] = nullptr;
      ga.C[0] = att; ga.K[0] = 768; ga.amode[0] = 1;
      ga.A0[1] = swg; ga.lda0[1] = 3072; ga.A1[1] = swg + 1536; ga.lda1[1] = 3072;
      ga.Bt[1] = WT_wout + (size_t)b * 768 * 1536; ga.bias[1] = nullptr;
      ga.C[1] = trout; ga.K[1] = 1536; ga.amode[1] = 2;
      ga.vT = nullptr;
      gemm_pair<<<dim3(6, 8, 2), B256, 0, stream>>>(ga, 768);
    }
    float* a_next = (b == NBLK - 1) ? (float*)d_out : a_buf;
    ew_final<<<768, B256, 0, stream>>>(sg_all + (size_t)b * 1536, att, trout, a_next);
    a_cur = a_next;
  }
}